// Round 14
// baseline (412.681 us; speedup 1.0000x reference)
//
#include <hip/hip_runtime.h>
#include <hip/hip_bf16.h>
#include <cstdint>
#include <cstddef>

#define PD 11
#define PP 121
#define NB 8

typedef _Float16 f16x8 __attribute__((ext_vector_type(8)));
typedef float    f32x4 __attribute__((ext_vector_type(4)));

#define GLOAD16(SRC, DST) __builtin_amdgcn_global_load_lds( \
    (const __attribute__((address_space(1))) void*)(SRC),   \
    (__attribute__((address_space(3))) void*)(DST), 16, 0, 0)

struct TinyArgs {
    const float* x[3]; const float* xp[3]; const float* h[3];
    const float* c[3]; const float* w[3]; const float* bi[3];
    float* oh[3]; float* oc[3];
};

// ---------------------------------------------------------------------------
__global__ void init_kernel(unsigned* __restrict__ slots, float* __restrict__ zg) {
    int t = threadIdx.x;
    if (t < 8) slots[t] = 0x007FFFFFu;  // enc(-inf)
    for (int i = t; i < 1024; i += 256) zg[i] = 0.f;
}

__device__ __forceinline__ float decode_max(const unsigned* slot) {
    unsigned mu = *slot;
    return (mu & 0x80000000u) ? __uint_as_float(mu ^ 0x80000000u) : __uint_as_float(~mu);
}

// ---------------------------------------------------------------------------
// fused fp32 NCHW -> fp16 NHWC transpose for x AND xp (blockIdx.z selects).
template<int C, int H, int TPX>
__global__ __launch_bounds__(256) void tpose_kernel(
    const float* __restrict__ xin, const float* __restrict__ xpin,
    _Float16* __restrict__ xT, _Float16* __restrict__ xpT)
{
    constexpr int W = H;
    const float* in  = blockIdx.z ? xpin : xin;
    _Float16*   out  = blockIdx.z ? xpT  : xT;
    const int by = blockIdx.y;
    const int b  = by / H, y = by % H;
    constexpr int NXT = W / TPX;
    const int x0 = (blockIdx.x % NXT) * TPX;
    const int cc = (blockIdx.x / NXT) * 64;
    __shared__ float s[64][36];

    constexpr int NF4 = 64 * TPX / 4;
    for (int f = threadIdx.x; f < NF4; f += 256) {
        int r  = f / (TPX / 4);
        int xq = f % (TPX / 4);
        int col = (xq * 4) ^ (((r >> 3) & 7) * 4);
        *(float4*)&s[r][col] =
            *(const float4*)&in[((size_t)(b * C + cc + r) * H + y) * W + x0 + xq * 4];
    }
    __syncthreads();
    constexpr int NWT = TPX * 8;
    for (int t = threadIdx.x; t < NWT; t += 256) {
        int pix = t >> 3, ck = t & 7;
        union { _Float16 h[8]; f16x8 v; } d;
#pragma unroll
        for (int j = 0; j < 8; ++j)
            d.h[j] = (_Float16)s[ck * 8 + j][pix ^ (ck * 4)];
        *(f16x8*)&out[((size_t)(b * H + y) * W + x0 + pix) * C + cc + ck * 8] = d.v;
    }
}

// ---------------------------------------------------------------------------
// MFMA correlation, double-buffered gload_lds staging. RAW leaky'd corr ->
// inT channels [0,128) + block max -> atomicMax.
template<int C, int H, int TSY, int TSX>
__global__ __launch_bounds__(512, 2) void corr_mfma_kernel(
    const _Float16* __restrict__ xT, const _Float16* __restrict__ xpT,
    const _Float16* __restrict__ zg,
    _Float16* __restrict__ inT, unsigned* __restrict__ slot)
{
    constexpr int W  = H;
    constexpr int HY = TSY + 10, HX = TSX + 10;
    constexpr int MZ = HY * HX;
    constexpr int MT = (MZ + 15) / 16;
    constexpr int MTP = MT * 16;
    constexpr int MFRAG = (MT + 7) / 8;
    constexpr int NPX = TSY * TSX;
    constexpr int NT  = NPX / 16;
    constexpr int KC  = C / 32;
    constexpr int ABYTES = MTP * 64;
    constexpr int BUF    = ABYTES + NPX * 64;
    constexpr int NLOAD  = BUF / 1024;
    constexpr int ST2    = NPX + 8;
    constexpr int ST_B   = MTP * ST2 * 2;
    constexpr int LDS_B  = (2 * BUF > ST_B) ? 2 * BUF : ST_B;
    __shared__ char smem[LDS_B];
    __shared__ float sred[8];

    const int tid  = threadIdx.x;
    const int b    = blockIdx.y;
    constexpr int TXT = W / TSX;
    const int y0 = (blockIdx.x / TXT) * TSY;
    const int x0 = (blockIdx.x % TXT) * TSX;
    const int w = tid >> 6, lane = tid & 63;
    const int lcol = lane & 15, lkg = lane >> 4;

    auto STAGE = [&](int bufsel, int kc) {
        char* dstb = smem + bufsel * BUF;
        int c = lane & 3;
        for (int it = w; it < NLOAD; it += 8) {
            const void* src;
            if (it < MTP / 16) {
                int z = it * 16 + (lane >> 2);
                int zy = y0 + z / HX - 5, zx = x0 + z % HX - 5;
                if (z < MZ && zy >= 0 && zy < H && zx >= 0 && zx < W)
                    src = xpT + ((size_t)(b * H + zy) * W + zx) * C + kc * 32 + ((c ^ (z >> 2)) & 3) * 8;
                else
                    src = zg + lane * 8;
            } else {
                int p = (it - MTP / 16) * 16 + (lane >> 2);
                int gy = y0 + p / TSX, gx = x0 + p % TSX;
                src = xT + ((size_t)(b * H + gy) * W + gx) * C + kc * 32 + ((c ^ (p >> 2)) & 3) * 8;
            }
            GLOAD16(src, dstb + it * 1024);
        }
    };

    f32x4 acc[MFRAG][NT];
#pragma unroll
    for (int i = 0; i < MFRAG; ++i)
#pragma unroll
        for (int nt = 0; nt < NT; ++nt)
            acc[i][nt] = (f32x4){0.f, 0.f, 0.f, 0.f};

    STAGE(0, 0);
    __syncthreads();
#pragma unroll 1
    for (int kc = 0; kc < KC; ++kc) {
        if (kc + 1 < KC) STAGE((kc + 1) & 1, kc + 1);
        const char* bb = smem + (kc & 1) * BUF;
        f16x8 bF[NT];
#pragma unroll
        for (int nt = 0; nt < NT; ++nt) {
            int p = nt * 16 + lcol;
            bF[nt] = *(const f16x8*)(bb + ABYTES + p * 64 + (((lkg ^ (p >> 2)) & 3) << 4));
        }
#pragma unroll
        for (int i = 0; i < MFRAG; ++i) {
            int mt = w + i * 8;
            if (mt < MT) {
                int z = mt * 16 + lcol;
                f16x8 aF = *(const f16x8*)(bb + z * 64 + (((lkg ^ (z >> 2)) & 3) << 4));
#pragma unroll
                for (int nt = 0; nt < NT; ++nt)
                    acc[i][nt] = __builtin_amdgcn_mfma_f32_16x16x32_f16(aF, bF[nt], acc[i][nt], 0, 0, 0);
            }
        }
        __syncthreads();
    }

    _Float16* sT = (_Float16*)smem;
#pragma unroll
    for (int i = 0; i < MFRAG; ++i) {
        int mt = w + i * 8;
        if (mt >= MT) continue;
        int z0 = mt * 16 + lkg * 4;
#pragma unroll
        for (int nt = 0; nt < NT; ++nt) {
            int p = nt * 16 + lcol;
#pragma unroll
            for (int r = 0; r < 4; ++r)
                sT[(z0 + r) * ST2 + p] = (_Float16)acc[i][nt][r];
        }
    }
    __syncthreads();

    float lmax = -3.4e38f;
    if (tid < NPX * 8) {
        int p  = tid >> 3;
        int qg = tid & 7;
        int py = p / TSX, px = p % TSX;
        size_t pix = (size_t)(b * H + y0 + py) * W + (x0 + px);
        unsigned* dst = (unsigned*)(inT + pix * 256) + qg * 8;
#pragma unroll
        for (int j2 = 0; j2 < 8; ++j2) {
            int q0 = qg * 16 + j2 * 2, q1 = q0 + 1;
            int qc0 = q0 < PP ? q0 : PP - 1;
            int qc1 = q1 < PP ? q1 : PP - 1;
            float v0 = (float)sT[((py + qc0 / PD) * HX + (px + qc0 % PD)) * ST2 + p];
            float v1 = (float)sT[((py + qc1 / PD) * HX + (px + qc1 % PD)) * ST2 + p];
            v0 = v0 > 0.f ? v0 : 0.01f * v0;
            v1 = v1 > 0.f ? v1 : 0.01f * v1;
            if (q0 < PP) lmax = fmaxf(lmax, v0);
            if (q1 < PP) lmax = fmaxf(lmax, v1);
            union { _Float16 h[2]; unsigned u; } pk;
            pk.h[0] = (_Float16)v0; pk.h[1] = (_Float16)v1;
            dst[j2] = pk.u;
        }
    }
    for (int off = 32; off; off >>= 1) lmax = fmaxf(lmax, __shfl_down(lmax, off));
    if (lane == 0) sred[w] = lmax;
    __syncthreads();
    if (tid == 0) {
        float m = sred[0];
        for (int i = 1; i < 8; ++i) m = fmaxf(m, sred[i]);
        unsigned eb = __float_as_uint(m);
        eb = (eb & 0x80000000u) ? ~eb : (eb | 0x80000000u);
        atomicMax(slot, eb);
    }
}

// ---------------------------------------------------------------------------
// coalesced weight pack body (LDS-staged, u32 fragment writes, prescale).
__device__ __forceinline__ void pack2_body(
    const float* __restrict__ Wsrc, _Float16* __restrict__ Apack,
    float inv, int mt, int ks, int tid, float* __restrict__ sW)
{
    const int icmax9 = (242 - ks * 32) * 9;
    for (int f = tid; f < 16 * 288; f += 256) {
        int r = f / 288, i = f - r * 288;
        int m = mt * 16 + r;
        float v = 0.f;
        if (m < 484 && i < icmax9) {
            int q = m >> 2, g = m & 3;
            v = Wsrc[((size_t)(g * PP + q) * 242 + ks * 32) * 9 + i];
        }
        sW[r * 292 + i] = v;
    }
    __syncthreads();
    const int o = tid * 2;
    const int l = o >> 3, e0 = o & 7;
    const int r = l & 15;
    const int klbase = (l >> 4) * 8;
    const int ic0 = ks * 32 + klbase + e0;
#pragma unroll 1
    for (int k9 = 0; k9 < 9; ++k9) {
        float v0 = sW[r * 292 + (klbase + e0) * 9 + k9];
        float v1 = sW[r * 292 + (klbase + e0 + 1) * 9 + k9];
        if (ic0 < PP)     v0 *= inv;
        if (ic0 + 1 < PP) v1 *= inv;
        union { _Float16 h[2]; unsigned u; } pk;
        pk.h[0] = (_Float16)v0; pk.h[1] = (_Float16)v1;
        *(unsigned*)((char*)Apack + (size_t)((k9 * 8 + ks) * 32 + mt) * 1024 + o * 2) = pk.u;
    }
}

// ---------------------------------------------------------------------------
// merged post-corr kernel for big levels: blocks [0,256) = pack, rest = h-fill.
template<int H>
__global__ __launch_bounds__(256) void post_kernel(
    _Float16* __restrict__ inT, const float* __restrict__ hpre,
    const float* __restrict__ Wsrc, _Float16* __restrict__ Apack,
    const unsigned* __restrict__ slot)
{
    __shared__ float sW[16 * 292];
    const int bx = blockIdx.x, tid = threadIdx.x;
    if (bx < 256) {
        float inv = 1.0f / decode_max(slot);
        pack2_body(Wsrc, Apack, inv, bx >> 3, bx & 7, tid, sW);
        return;
    }
    constexpr int HW = H * H;
    constexpr int NP = NB * HW;
    int idx = (bx - 256) * 256 + tid;
    if (idx >= NP * 17) return;
    int c = 15 + idx / NP;
    int pix = idx % NP;
    int b = pix / HW, p2 = pix % HW;
    _Float16* base = inT + (size_t)pix * 256 + c * 8;
    union { _Float16 h[8]; uint4 u; } d;
    if (c == 15) {
        d.u = *(const uint4*)base;
#pragma unroll
        for (int j = 1; j < 8; ++j)
            d.h[j] = (_Float16)hpre[((size_t)b * PP + (j - 1)) * HW + p2];
    } else if (c <= 29) {
#pragma unroll
        for (int j = 0; j < 8; ++j)
            d.h[j] = (_Float16)hpre[((size_t)b * PP + (c * 8 + j - 121)) * HW + p2];
    } else if (c == 30) {
        d.h[0] = (_Float16)hpre[((size_t)b * PP + 119) * HW + p2];
        d.h[1] = (_Float16)hpre[((size_t)b * PP + 120) * HW + p2];
#pragma unroll
        for (int j = 2; j < 8; ++j) d.h[j] = (_Float16)0.f;
    } else {
#pragma unroll
        for (int j = 0; j < 8; ++j) d.h[j] = (_Float16)0.f;
    }
    *(uint4*)base = d.u;
}

// ---------------------------------------------------------------------------
// tiny levels (H=8/4/2): corr and h-fill in SEPARATE launches.
template<int H>
__device__ void corr_small_body(const float* __restrict__ x, const float* __restrict__ xp,
    _Float16* __restrict__ inT, unsigned* __restrict__ slot, int b)
{
    constexpr int PX  = H * H;
    constexpr int TOT = PX * PP;
    const int o = blockIdx.x * 256 + threadIdx.x;
    float v = -3.4e38f;
    if (o < TOT) {
        int p = o / PP;
        int q = o - p * PP;
        int y = p / H, xx = p % H;
        int sy = y + q / PD - 5, sx = xx + q % PD - 5;
        float acc = 0.f;
        if (sy >= 0 && sy < H && sx >= 0 && sx < H) {
            const float* xb  = x  + (size_t)b * 256 * PX + p;
            const float* xpb = xp + (size_t)b * 256 * PX + sy * H + sx;
#pragma unroll 8
            for (int c = 0; c < 256; ++c)
                acc = fmaf(xb[c * PX], xpb[c * PX], acc);
        }
        float lv = acc > 0.f ? acc : 0.01f * acc;
        inT[((size_t)b * PX + p) * 256 + q] = (_Float16)lv;
        v = lv;
    }
    for (int off = 32; off; off >>= 1) v = fmaxf(v, __shfl_down(v, off));
    __shared__ float sred[4];
    if ((threadIdx.x & 63) == 0) sred[threadIdx.x >> 6] = v;
    __syncthreads();
    if (threadIdx.x == 0) {
        float m = fmaxf(fmaxf(sred[0], sred[1]), fmaxf(sred[2], sred[3]));
        unsigned eb = __float_as_uint(m);
        eb = (eb & 0x80000000u) ? ~eb : (eb | 0x80000000u);
        atomicMax(slot, eb);
    }
}

template<int H>
__device__ void hfill_body(_Float16* __restrict__ inT, const float* __restrict__ hpre, int b)
{
    constexpr int HW = H * H;
    int idx = blockIdx.x * 256 + threadIdx.x;
    if (idx >= HW * 17) return;
    int c = 15 + idx / HW;
    int p2 = idx % HW;
    _Float16* base = inT + ((size_t)b * HW + p2) * 256 + c * 8;
    union { _Float16 h[8]; uint4 u; } d;
    if (c == 15) {
        d.u = *(const uint4*)base;
#pragma unroll
        for (int j = 1; j < 8; ++j)
            d.h[j] = (_Float16)hpre[((size_t)b * PP + (j - 1)) * HW + p2];
    } else if (c <= 29) {
#pragma unroll
        for (int j = 0; j < 8; ++j)
            d.h[j] = (_Float16)hpre[((size_t)b * PP + (c * 8 + j - 121)) * HW + p2];
    } else if (c == 30) {
        d.h[0] = (_Float16)hpre[((size_t)b * PP + 119) * HW + p2];
        d.h[1] = (_Float16)hpre[((size_t)b * PP + 120) * HW + p2];
#pragma unroll
        for (int j = 2; j < 8; ++j) d.h[j] = (_Float16)0.f;
    } else {
#pragma unroll
        for (int j = 0; j < 8; ++j) d.h[j] = (_Float16)0.f;
    }
    *(uint4*)base = d.u;
}

__global__ __launch_bounds__(256) void tiny_corr_kernel(
    TinyArgs ta, _Float16* __restrict__ inT, unsigned* __restrict__ slots)
{
    const int z = blockIdx.z, b = blockIdx.y;
    if      (z == 0) corr_small_body<8>(ta.x[0], ta.xp[0], inT,          slots + 3, b);
    else if (z == 1) corr_small_body<4>(ta.x[1], ta.xp[1], inT + 131072, slots + 4, b);
    else             corr_small_body<2>(ta.x[2], ta.xp[2], inT + 163840, slots + 5, b);
}

__global__ __launch_bounds__(256) void tiny_hfill_kernel(
    TinyArgs ta, _Float16* __restrict__ inT)
{
    const int z = blockIdx.z, b = blockIdx.y;
    if      (z == 0) hfill_body<8>(inT,          ta.h[0], b);
    else if (z == 1) hfill_body<4>(inT + 131072, ta.h[1], b);
    else             hfill_body<2>(inT + 163840, ta.h[2], b);
}

__global__ __launch_bounds__(256) void pack_tiny_kernel(
    TinyArgs ta, _Float16* __restrict__ a0, _Float16* __restrict__ a1,
    _Float16* __restrict__ a2, const unsigned* __restrict__ slots)
{
    __shared__ float sW[16 * 292];
    const int z = blockIdx.z;
    _Float16* Ap = (z == 0) ? a0 : (z == 1 ? a1 : a2);
    float inv = 1.0f / decode_max(slots + 3 + z);
    pack2_body(ta.w[z], Ap, inv, blockIdx.x >> 3, blockIdx.x & 7, threadIdx.x, sW);
}

// ---------------------------------------------------------------------------
// conv v3: TR x 16 tile, gload_lds staging, A-fragment register TRIPLE-buffer
// (prefetch distance 2 covers ~300cyc L2 latency; r13 dbuf covered only ~150).
template<int H, int TR, int MSPLIT>
__global__ __launch_bounds__(512, 4) void conv_mfma3_kernel(
    const _Float16* __restrict__ inT, const float* __restrict__ cpre,
    const _Float16* __restrict__ Apack, const float* __restrict__ bias,
    const _Float16* __restrict__ zg,
    float* __restrict__ outh, float* __restrict__ outc)
{
    constexpr int W = H;
    constexpr int TC = 16, SR = TC + 2;
    constexpr int NPOS = (TR + 2) * SR;
    constexpr int MT_BLK = 32 / MSPLIT;
    constexpr int AF = 4 / MSPLIT;
    constexpr int TILES_X = W / TC;
    __shared__ _Float16 sIn[NPOS * 256];

    const int tid  = threadIdx.x;
    const int b    = blockIdx.y;
    const int mblk = blockIdx.z;
    const int tile = blockIdx.x;
    const int ty0  = (tile / TILES_X) * TR;
    const int tx0  = (tile % TILES_X) * TC;
    const int w = tid >> 6, lane = tid & 63;
    const int lcol = lane & 15, kg = lane >> 4;

    char* sB = (char*)sIn;
    for (int it = w; it < NPOS / 2; it += 8) {
        int r  = it * 2 + (lane >> 5);
        int c  = lane & 31;
        int iy = r / SR, ix = r % SR;
        int gy = ty0 + iy - 1, gx = tx0 + ix - 1;
        const void* src;
        if (gy >= 0 && gy < H && gx >= 0 && gx < W)
            src = inT + ((size_t)(b * H + gy) * W + gx) * 256 + (c ^ (ix & 7)) * 8;
        else
            src = zg + lane * 8;
        GLOAD16(src, sB + it * 1024);
    }
    __syncthreads();

    const int mtg0 = mblk * MT_BLK + w * AF;

    f32x4 acc[AF * TR];
#pragma unroll
    for (int a = 0; a < AF; ++a) {
        int q = (mtg0 + a) * 4 + kg;
        f32x4 bv;
#pragma unroll
        for (int r = 0; r < 4; ++r) bv[r] = (q < PP) ? bias[r * PP + q] : 0.f;
#pragma unroll
        for (int j = 0; j < TR; ++j) acc[a * TR + j] = bv;
    }

    const f16x8* apL = (const f16x8*)Apack + (size_t)mtg0 * 64 + lane;

    auto LOADA = [&](f16x8* af, int s) {
        const f16x8* ap = apL + (size_t)s * 2048;
#pragma unroll
        for (int a = 0; a < AF; ++a) af[a] = ap[a * 64];
    };
    auto COMPUTE = [&](const f16x8* af, int s) {
        int k9 = s >> 3, ks = s & 7;
        int ky = k9 / 3, kx = k9 - ky * 3;
        int ix = lcol + kx;
        int xsw = (ix & 7) << 4;
        int cb  = kg * 16 + ks * 64;
#pragma unroll
        for (int j = 0; j < TR; ++j) {
            int addr = ((((j + ky) * SR + ix) * 512) + cb) ^ xsw;
            f16x8 bf = *(const f16x8*)(sB + addr);
#pragma unroll
            for (int a = 0; a < AF; ++a)
                acc[a * TR + j] = __builtin_amdgcn_mfma_f32_16x16x32_f16(af[a], bf, acc[a * TR + j], 0, 0, 0);
        }
    };

    // 72-step loop; A triple-buffer, prefetch distance 2 (static names).
    f16x8 afA[AF], afB[AF], afC[AF];
    LOADA(afA, 0);
    LOADA(afB, 1);
#pragma unroll 1
    for (int s3 = 0; s3 < 24; ++s3) {
        int s = s3 * 3;
        LOADA(afC, s + 2);
        COMPUTE(afA, s);
        if (s3 < 23) LOADA(afA, s + 3);
        COMPUTE(afB, s + 1);
        if (s3 < 23) LOADA(afB, s + 4);
        COMPUTE(afC, s + 2);
    }

#pragma unroll
    for (int a = 0; a < AF; ++a) {
        int q = (mtg0 + a) * 4 + kg;
        if (q >= PP) continue;
#pragma unroll
        for (int j = 0; j < TR; ++j) {
            int y = ty0 + j, x = tx0 + lcol;
            if (y >= H) continue;
            float ai = acc[a * TR + j][0];
            float af_ = acc[a * TR + j][1];
            float ao = acc[a * TR + j][2];
            float ag = acc[a * TR + j][3];
            float ig = 1.f / (1.f + expf(-ai));
            float fg = 1.f / (1.f + expf(-af_));
            float og = 1.f / (1.f + expf(-ao));
            float gg = tanhf(ag);
            size_t oidx = (((size_t)b * PP + q) * H + y) * W + x;
            float cp = cpre[oidx];
            float cn = fg * cp + ig * gg;
            outh[oidx] = og * tanhf(cn);
            outc[oidx] = cn;
        }
    }
}

// ---------------------------------------------------------------------------
// batched tiny conv: whole image per block, M-split over blockIdx.x, level
// over blockIdx.z.
template<int H>
__device__ void conv_tiny_body(const _Float16* __restrict__ inT,
    const float* __restrict__ cpre, const _Float16* __restrict__ Apack,
    const float* __restrict__ bias, float* __restrict__ outh,
    float* __restrict__ outc, int b, int mblk, char* __restrict__ sB)
{
    constexpr int NPX = H * H;
    constexpr int NT  = (NPX + 15) / 16;
    constexpr int SR  = H + 2;
    constexpr int NPOS = SR * SR;
    const int tid = threadIdx.x;

    constexpr int CHUNKS = NPOS * 32;
    for (int flat = tid; flat < CHUNKS; flat += 512) {
        int cg  = flat & 31;
        int pos = flat >> 5;
        int iy = pos / SR, ix = pos % SR;
        int gy = iy - 1, gx = ix - 1;
        f16x8 v = {0, 0, 0, 0, 0, 0, 0, 0};
        if (gy >= 0 && gy < H && gx >= 0 && gx < H)
            v = *(const f16x8*)(inT + ((size_t)(b * H + gy) * H + gx) * 256 + cg * 8);
        int dst = (pos * 512 + cg * 16) ^ ((ix & 7) << 4);
        *(f16x8*)(sB + dst) = v;
    }
    __syncthreads();

    const int w = tid >> 6, lane = tid & 63;
    const int lcol = lane & 15, kg = lane >> 4;
    const int mt = mblk * 8 + w;
    const int q  = mt * 4 + kg;

    f32x4 acc[NT];
    f32x4 bv;
#pragma unroll
    for (int r = 0; r < 4; ++r) bv[r] = (q < PP) ? bias[r * PP + q] : 0.f;
#pragma unroll
    for (int nt = 0; nt < NT; ++nt) acc[nt] = bv;

#pragma unroll 1
    for (int k9 = 0; k9 < 9; ++k9) {
        const int ky = k9 / 3, kx = k9 % 3;
        int basev[NT], xswv[NT];
#pragma unroll
        for (int nt = 0; nt < NT; ++nt) {
            int p = nt * 16 + lcol;
            int pc = (NPX < 16 && p >= NPX) ? 0 : p;
            int py = pc / H, px = pc % H;
            int iy = py + ky, ix = px + kx;
            basev[nt] = (iy * SR + ix) * 512 + kg * 16;
            xswv[nt]  = (ix & 7) << 4;
        }
        const f16x8* apb = (const f16x8*)Apack + ((size_t)(k9 * 8) * 32 + mt) * 64 + lane;
#pragma unroll 1
        for (int ks = 0; ks < 8; ++ks) {
            f16x8 bf[NT];
#pragma unroll
            for (int nt = 0; nt < NT; ++nt) {
                bf[nt] = *(const f16x8*)(sB + ((basev[nt] + ks * 64) ^ xswv[nt]));
                if (NPX < 16 && nt * 16 + lcol >= NPX) bf[nt] = (f16x8){};
            }
            f16x8 af = apb[(size_t)ks * 32 * 64];
#pragma unroll
            for (int nt = 0; nt < NT; ++nt)
                acc[nt] = __builtin_amdgcn_mfma_f32_16x16x32_f16(af, bf[nt], acc[nt], 0, 0, 0);
        }
    }

    if (q < PP) {
#pragma unroll
        for (int nt = 0; nt < NT; ++nt) {
            int p = nt * 16 + lcol;
            if (NPX < 16 && p >= NPX) continue;
            int py = p / H, px = p % H;
            float ai = acc[nt][0];
            float af_ = acc[nt][1];
            float ao = acc[nt][2];
            float ag = acc[nt][3];
            float ig = 1.f / (1.f + expf(-ai));
            float fg = 1.f / (1.f + expf(-af_));
            float og = 1.f / (1.f + expf(-ao));
            float gg = tanhf(ag);
            size_t oidx = (((size_t)b * PP + q) * H + py) * H + px;
            float cp = cpre[oidx];
            float cn = fg * cp + ig * gg;
            outh[oidx] = og * tanhf(cn);
            outc[oidx] = cn;
        }
    }
}

__global__ __launch_bounds__(512, 4) void conv_tiny_kernel(
    TinyArgs ta, const _Float16* __restrict__ inT,
    const _Float16* __restrict__ a0, const _Float16* __restrict__ a1,
    const _Float16* __restrict__ a2)
{
    __shared__ char sB[100 * 512];
    const int z = blockIdx.z, b = blockIdx.y, mblk = blockIdx.x;
    if      (z == 0) conv_tiny_body<8>(inT,          ta.c[0], a0, ta.bi[0], ta.oh[0], ta.oc[0], b, mblk, sB);
    else if (z == 1) conv_tiny_body<4>(inT + 131072, ta.c[1], a1, ta.bi[1], ta.oh[1], ta.oc[1], b, mblk, sB);
    else             conv_tiny_body<2>(inT + 163840, ta.c[2], a2, ta.bi[2], ta.oh[2], ta.oc[2], b, mblk, sB);
}

// ---------------------------------------------------------------------------
extern "C" void kernel_launch(void* const* d_in, const int* in_sizes, int n_in,
                              void* d_out, int out_size, void* d_ws, size_t ws_size,
                              hipStream_t stream) {
    (void)in_sizes; (void)n_in; (void)out_size; (void)ws_size;
    static const int HH[6] = {64, 32, 16, 8, 4, 2};

    unsigned* maxslots = (unsigned*)d_ws;
    _Float16* Apack = (_Float16*)((char*)d_ws + 256);
    _Float16* inT   = (_Float16*)((char*)d_ws + 2359808);
    _Float16* xT    = (_Float16*)((char*)d_ws + 19137024);
    _Float16* xpT   = (_Float16*)((char*)d_ws + 52691456);
    _Float16* zg    = (_Float16*)((char*)d_ws + 86245888);
    _Float16* apT0 = (_Float16*)((char*)d_ws + 19137024);
    _Float16* apT1 = (_Float16*)((char*)d_ws + 19137024 + 2359296);
    _Float16* apT2 = (_Float16*)((char*)d_ws + 19137024 + 2 * 2359296);

    float* out = (float*)d_out;
    size_t obase[6];
    {
        size_t ob = 0;
        for (int L = 0; L < 6; ++L) { obase[L] = ob; ob += 2ull * NB * PP * HH[L] * HH[L]; }
    }

    init_kernel<<<1, 256, 0, stream>>>(maxslots, (float*)zg);

    // ---- big levels 0..2 ----
    for (int L = 0; L < 3; ++L) {
        const float* x    = (const float*)d_in[6 * L + 0];
        const float* xp   = (const float*)d_in[6 * L + 1];
        const float* h    = (const float*)d_in[6 * L + 2];
        const float* c    = (const float*)d_in[6 * L + 3];
        const float* Wsrc = (const float*)d_in[6 * L + 4];
        const float* bias = (const float*)d_in[6 * L + 5];
        int Hh = HH[L];
        int S = NB * PP * Hh * Hh;
        float* oh = out + obase[L];
        float* oc = out + obase[L] + S;

        switch (L) {
            case 0:
                tpose_kernel<512, 64, 32><<<dim3(16, NB * 64, 2), 256, 0, stream>>>(x, xp, xT, xpT);
                corr_mfma_kernel<512, 64, 8, 8><<<dim3(64, NB), 512, 0, stream>>>(xT, xpT, zg, inT, maxslots + 0);
                post_kernel<64><<<256 + (NB * 64 * 64 * 17 + 255) / 256, 256, 0, stream>>>(inT, h, Wsrc, Apack, maxslots + 0);
                conv_mfma3_kernel<64, 4, 1><<<dim3(64, 8, 1), 512, 0, stream>>>(inT, c, Apack, bias, zg, oh, oc);
                break;
            case 1:
                tpose_kernel<1024, 32, 32><<<dim3(16, NB * 32, 2), 256, 0, stream>>>(x, xp, xT, xpT);
                corr_mfma_kernel<1024, 32, 4, 8><<<dim3(32, NB), 512, 0, stream>>>(xT, xpT, zg, inT, maxslots + 1);
                post_kernel<32><<<256 + (NB * 32 * 32 * 17 + 255) / 256, 256, 0, stream>>>(inT, h, Wsrc, Apack, maxslots + 1);
                conv_mfma3_kernel<32, 4, 2><<<dim3(16, 8, 2), 512, 0, stream>>>(inT, c, Apack, bias, zg, oh, oc);
                break;
            case 2:
                tpose_kernel<512, 16, 16><<<dim3(8, NB * 16, 2), 256, 0, stream>>>(x, xp, xT, xpT);
                corr_mfma_kernel<512, 16, 4, 4><<<dim3(16, NB), 512, 0, stream>>>(xT, xpT, zg, inT, maxslots + 2);
                post_kernel<16><<<256 + (NB * 16 * 16 * 17 + 255) / 256, 256, 0, stream>>>(inT, h, Wsrc, Apack, maxslots + 2);
                conv_mfma3_kernel<16, 4, 4><<<dim3(4, 8, 4), 512, 0, stream>>>(inT, c, Apack, bias, zg, oh, oc);
                break;
        }
    }

    // ---- tiny levels 3..5, batched ----
    TinyArgs ta;
    for (int i = 0; i < 3; ++i) {
        int L = 3 + i;
        ta.x[i]  = (const float*)d_in[6 * L + 0];
        ta.xp[i] = (const float*)d_in[6 * L + 1];
        ta.h[i]  = (const float*)d_in[6 * L + 2];
        ta.c[i]  = (const float*)d_in[6 * L + 3];
        ta.w[i]  = (const float*)d_in[6 * L + 4];
        ta.bi[i] = (const float*)d_in[6 * L + 5];
        int S = NB * PP * HH[L] * HH[L];
        ta.oh[i] = out + obase[L];
        ta.oc[i] = out + obase[L] + S;
    }
    tiny_corr_kernel<<<dim3(31, NB, 3), 256, 0, stream>>>(ta, inT, maxslots);
    tiny_hfill_kernel<<<dim3(5, NB, 3), 256, 0, stream>>>(ta, inT);
    pack_tiny_kernel<<<dim3(256, 1, 3), 256, 0, stream>>>(ta, apT0, apT1, apT2, maxslots);
    conv_tiny_kernel<<<dim3(4, NB, 3), 512, 0, stream>>>(ta, inT, apT0, apT1, apT2);
}

// Round 15
// 383.002 us; speedup vs baseline: 1.0775x; 1.0775x over previous
//
#include <hip/hip_runtime.h>
#include <hip/hip_bf16.h>
#include <cstdint>
#include <cstddef>

#define PD 11
#define PP 121
#define NB 8

typedef _Float16 f16x8 __attribute__((ext_vector_type(8)));
typedef float    f32x4 __attribute__((ext_vector_type(4)));

#define GLOAD16(SRC, DST) __builtin_amdgcn_global_load_lds( \
    (const __attribute__((address_space(1))) void*)(SRC),   \
    (__attribute__((address_space(3))) void*)(DST), 16, 0, 0)

struct TinyArgs {
    const float* x[3]; const float* xp[3]; const float* h[3];
    const float* c[3]; const float* w[3]; const float* bi[3];
    float* oh[3]; float* oc[3];
};

// ---------------------------------------------------------------------------
__global__ void init_kernel(unsigned* __restrict__ slots, float* __restrict__ zg) {
    int t = threadIdx.x;
    if (t < 8) slots[t] = 0x007FFFFFu;  // enc(-inf)
    for (int i = t; i < 1024; i += 256) zg[i] = 0.f;
}

__device__ __forceinline__ float decode_max(const unsigned* slot) {
    unsigned mu = *slot;
    return (mu & 0x80000000u) ? __uint_as_float(mu ^ 0x80000000u) : __uint_as_float(~mu);
}

// ---------------------------------------------------------------------------
// fused fp32 NCHW -> fp16 NHWC transpose for x AND xp (blockIdx.z selects).
template<int C, int H, int TPX>
__global__ __launch_bounds__(256) void tpose_kernel(
    const float* __restrict__ xin, const float* __restrict__ xpin,
    _Float16* __restrict__ xT, _Float16* __restrict__ xpT)
{
    constexpr int W = H;
    const float* in  = blockIdx.z ? xpin : xin;
    _Float16*   out  = blockIdx.z ? xpT  : xT;
    const int by = blockIdx.y;
    const int b  = by / H, y = by % H;
    constexpr int NXT = W / TPX;
    const int x0 = (blockIdx.x % NXT) * TPX;
    const int cc = (blockIdx.x / NXT) * 64;
    __shared__ float s[64][36];

    constexpr int NF4 = 64 * TPX / 4;
    for (int f = threadIdx.x; f < NF4; f += 256) {
        int r  = f / (TPX / 4);
        int xq = f % (TPX / 4);
        int col = (xq * 4) ^ (((r >> 3) & 7) * 4);
        *(float4*)&s[r][col] =
            *(const float4*)&in[((size_t)(b * C + cc + r) * H + y) * W + x0 + xq * 4];
    }
    __syncthreads();
    constexpr int NWT = TPX * 8;
    for (int t = threadIdx.x; t < NWT; t += 256) {
        int pix = t >> 3, ck = t & 7;
        union { _Float16 h[8]; f16x8 v; } d;
#pragma unroll
        for (int j = 0; j < 8; ++j)
            d.h[j] = (_Float16)s[ck * 8 + j][pix ^ (ck * 4)];
        *(f16x8*)&out[((size_t)(b * H + y) * W + x0 + pix) * C + cc + ck * 8] = d.v;
    }
}

// ---------------------------------------------------------------------------
// MFMA correlation, double-buffered gload_lds staging. RAW leaky'd corr ->
// inT channels [0,128) + block max -> atomicMax.
template<int C, int H, int TSY, int TSX>
__global__ __launch_bounds__(512, 2) void corr_mfma_kernel(
    const _Float16* __restrict__ xT, const _Float16* __restrict__ xpT,
    const _Float16* __restrict__ zg,
    _Float16* __restrict__ inT, unsigned* __restrict__ slot)
{
    constexpr int W  = H;
    constexpr int HY = TSY + 10, HX = TSX + 10;
    constexpr int MZ = HY * HX;
    constexpr int MT = (MZ + 15) / 16;
    constexpr int MTP = MT * 16;
    constexpr int MFRAG = (MT + 7) / 8;
    constexpr int NPX = TSY * TSX;
    constexpr int NT  = NPX / 16;
    constexpr int KC  = C / 32;
    constexpr int ABYTES = MTP * 64;
    constexpr int BUF    = ABYTES + NPX * 64;
    constexpr int NLOAD  = BUF / 1024;
    constexpr int ST2    = NPX + 8;
    constexpr int ST_B   = MTP * ST2 * 2;
    constexpr int LDS_B  = (2 * BUF > ST_B) ? 2 * BUF : ST_B;
    __shared__ char smem[LDS_B];
    __shared__ float sred[8];

    const int tid  = threadIdx.x;
    const int b    = blockIdx.y;
    constexpr int TXT = W / TSX;
    const int y0 = (blockIdx.x / TXT) * TSY;
    const int x0 = (blockIdx.x % TXT) * TSX;
    const int w = tid >> 6, lane = tid & 63;
    const int lcol = lane & 15, lkg = lane >> 4;

    auto STAGE = [&](int bufsel, int kc) {
        char* dstb = smem + bufsel * BUF;
        int c = lane & 3;
        for (int it = w; it < NLOAD; it += 8) {
            const void* src;
            if (it < MTP / 16) {
                int z = it * 16 + (lane >> 2);
                int zy = y0 + z / HX - 5, zx = x0 + z % HX - 5;
                if (z < MZ && zy >= 0 && zy < H && zx >= 0 && zx < W)
                    src = xpT + ((size_t)(b * H + zy) * W + zx) * C + kc * 32 + ((c ^ (z >> 2)) & 3) * 8;
                else
                    src = zg + lane * 8;
            } else {
                int p = (it - MTP / 16) * 16 + (lane >> 2);
                int gy = y0 + p / TSX, gx = x0 + p % TSX;
                src = xT + ((size_t)(b * H + gy) * W + gx) * C + kc * 32 + ((c ^ (p >> 2)) & 3) * 8;
            }
            GLOAD16(src, dstb + it * 1024);
        }
    };

    f32x4 acc[MFRAG][NT];
#pragma unroll
    for (int i = 0; i < MFRAG; ++i)
#pragma unroll
        for (int nt = 0; nt < NT; ++nt)
            acc[i][nt] = (f32x4){0.f, 0.f, 0.f, 0.f};

    STAGE(0, 0);
    __syncthreads();
#pragma unroll 1
    for (int kc = 0; kc < KC; ++kc) {
        if (kc + 1 < KC) STAGE((kc + 1) & 1, kc + 1);
        const char* bb = smem + (kc & 1) * BUF;
        f16x8 bF[NT];
#pragma unroll
        for (int nt = 0; nt < NT; ++nt) {
            int p = nt * 16 + lcol;
            bF[nt] = *(const f16x8*)(bb + ABYTES + p * 64 + (((lkg ^ (p >> 2)) & 3) << 4));
        }
#pragma unroll
        for (int i = 0; i < MFRAG; ++i) {
            int mt = w + i * 8;
            if (mt < MT) {
                int z = mt * 16 + lcol;
                f16x8 aF = *(const f16x8*)(bb + z * 64 + (((lkg ^ (z >> 2)) & 3) << 4));
#pragma unroll
                for (int nt = 0; nt < NT; ++nt)
                    acc[i][nt] = __builtin_amdgcn_mfma_f32_16x16x32_f16(aF, bF[nt], acc[i][nt], 0, 0, 0);
            }
        }
        __syncthreads();
    }

    _Float16* sT = (_Float16*)smem;
#pragma unroll
    for (int i = 0; i < MFRAG; ++i) {
        int mt = w + i * 8;
        if (mt >= MT) continue;
        int z0 = mt * 16 + lkg * 4;
#pragma unroll
        for (int nt = 0; nt < NT; ++nt) {
            int p = nt * 16 + lcol;
#pragma unroll
            for (int r = 0; r < 4; ++r)
                sT[(z0 + r) * ST2 + p] = (_Float16)acc[i][nt][r];
        }
    }
    __syncthreads();

    float lmax = -3.4e38f;
    if (tid < NPX * 8) {
        int p  = tid >> 3;
        int qg = tid & 7;
        int py = p / TSX, px = p % TSX;
        size_t pix = (size_t)(b * H + y0 + py) * W + (x0 + px);
        unsigned* dst = (unsigned*)(inT + pix * 256) + qg * 8;
#pragma unroll
        for (int j2 = 0; j2 < 8; ++j2) {
            int q0 = qg * 16 + j2 * 2, q1 = q0 + 1;
            int qc0 = q0 < PP ? q0 : PP - 1;
            int qc1 = q1 < PP ? q1 : PP - 1;
            float v0 = (float)sT[((py + qc0 / PD) * HX + (px + qc0 % PD)) * ST2 + p];
            float v1 = (float)sT[((py + qc1 / PD) * HX + (px + qc1 % PD)) * ST2 + p];
            v0 = v0 > 0.f ? v0 : 0.01f * v0;
            v1 = v1 > 0.f ? v1 : 0.01f * v1;
            if (q0 < PP) lmax = fmaxf(lmax, v0);
            if (q1 < PP) lmax = fmaxf(lmax, v1);
            union { _Float16 h[2]; unsigned u; } pk;
            pk.h[0] = (_Float16)v0; pk.h[1] = (_Float16)v1;
            dst[j2] = pk.u;
        }
    }
    for (int off = 32; off; off >>= 1) lmax = fmaxf(lmax, __shfl_down(lmax, off));
    if (lane == 0) sred[w] = lmax;
    __syncthreads();
    if (tid == 0) {
        float m = sred[0];
        for (int i = 1; i < 8; ++i) m = fmaxf(m, sred[i]);
        unsigned eb = __float_as_uint(m);
        eb = (eb & 0x80000000u) ? ~eb : (eb | 0x80000000u);
        atomicMax(slot, eb);
    }
}

// ---------------------------------------------------------------------------
// coalesced weight pack body (LDS-staged, u32 fragment writes, prescale).
__device__ __forceinline__ void pack2_body(
    const float* __restrict__ Wsrc, _Float16* __restrict__ Apack,
    float inv, int mt, int ks, int tid, float* __restrict__ sW)
{
    const int icmax9 = (242 - ks * 32) * 9;
    for (int f = tid; f < 16 * 288; f += 256) {
        int r = f / 288, i = f - r * 288;
        int m = mt * 16 + r;
        float v = 0.f;
        if (m < 484 && i < icmax9) {
            int q = m >> 2, g = m & 3;
            v = Wsrc[((size_t)(g * PP + q) * 242 + ks * 32) * 9 + i];
        }
        sW[r * 292 + i] = v;
    }
    __syncthreads();
    const int o = tid * 2;
    const int l = o >> 3, e0 = o & 7;
    const int r = l & 15;
    const int klbase = (l >> 4) * 8;
    const int ic0 = ks * 32 + klbase + e0;
#pragma unroll 1
    for (int k9 = 0; k9 < 9; ++k9) {
        float v0 = sW[r * 292 + (klbase + e0) * 9 + k9];
        float v1 = sW[r * 292 + (klbase + e0 + 1) * 9 + k9];
        if (ic0 < PP)     v0 *= inv;
        if (ic0 + 1 < PP) v1 *= inv;
        union { _Float16 h[2]; unsigned u; } pk;
        pk.h[0] = (_Float16)v0; pk.h[1] = (_Float16)v1;
        *(unsigned*)((char*)Apack + (size_t)((k9 * 8 + ks) * 32 + mt) * 1024 + o * 2) = pk.u;
    }
}

// ---------------------------------------------------------------------------
// merged post-corr kernel for big levels: blocks [0,256) = pack, rest = h-fill.
template<int H>
__global__ __launch_bounds__(256) void post_kernel(
    _Float16* __restrict__ inT, const float* __restrict__ hpre,
    const float* __restrict__ Wsrc, _Float16* __restrict__ Apack,
    const unsigned* __restrict__ slot)
{
    __shared__ float sW[16 * 292];
    const int bx = blockIdx.x, tid = threadIdx.x;
    if (bx < 256) {
        float inv = 1.0f / decode_max(slot);
        pack2_body(Wsrc, Apack, inv, bx >> 3, bx & 7, tid, sW);
        return;
    }
    constexpr int HW = H * H;
    constexpr int NP = NB * HW;
    int idx = (bx - 256) * 256 + tid;
    if (idx >= NP * 17) return;
    int c = 15 + idx / NP;
    int pix = idx % NP;
    int b = pix / HW, p2 = pix % HW;
    _Float16* base = inT + (size_t)pix * 256 + c * 8;
    union { _Float16 h[8]; uint4 u; } d;
    if (c == 15) {
        d.u = *(const uint4*)base;
#pragma unroll
        for (int j = 1; j < 8; ++j)
            d.h[j] = (_Float16)hpre[((size_t)b * PP + (j - 1)) * HW + p2];
    } else if (c <= 29) {
#pragma unroll
        for (int j = 0; j < 8; ++j)
            d.h[j] = (_Float16)hpre[((size_t)b * PP + (c * 8 + j - 121)) * HW + p2];
    } else if (c == 30) {
        d.h[0] = (_Float16)hpre[((size_t)b * PP + 119) * HW + p2];
        d.h[1] = (_Float16)hpre[((size_t)b * PP + 120) * HW + p2];
#pragma unroll
        for (int j = 2; j < 8; ++j) d.h[j] = (_Float16)0.f;
    } else {
#pragma unroll
        for (int j = 0; j < 8; ++j) d.h[j] = (_Float16)0.f;
    }
    *(uint4*)base = d.u;
}

// ---------------------------------------------------------------------------
// tiny levels (H=8/4/2): corr and h-fill in SEPARATE launches.
template<int H>
__device__ void corr_small_body(const float* __restrict__ x, const float* __restrict__ xp,
    _Float16* __restrict__ inT, unsigned* __restrict__ slot, int b)
{
    constexpr int PX  = H * H;
    constexpr int TOT = PX * PP;
    const int o = blockIdx.x * 256 + threadIdx.x;
    float v = -3.4e38f;
    if (o < TOT) {
        int p = o / PP;
        int q = o - p * PP;
        int y = p / H, xx = p % H;
        int sy = y + q / PD - 5, sx = xx + q % PD - 5;
        float acc = 0.f;
        if (sy >= 0 && sy < H && sx >= 0 && sx < H) {
            const float* xb  = x  + (size_t)b * 256 * PX + p;
            const float* xpb = xp + (size_t)b * 256 * PX + sy * H + sx;
#pragma unroll 8
            for (int c = 0; c < 256; ++c)
                acc = fmaf(xb[c * PX], xpb[c * PX], acc);
        }
        float lv = acc > 0.f ? acc : 0.01f * acc;
        inT[((size_t)b * PX + p) * 256 + q] = (_Float16)lv;
        v = lv;
    }
    for (int off = 32; off; off >>= 1) v = fmaxf(v, __shfl_down(v, off));
    __shared__ float sred[4];
    if ((threadIdx.x & 63) == 0) sred[threadIdx.x >> 6] = v;
    __syncthreads();
    if (threadIdx.x == 0) {
        float m = fmaxf(fmaxf(sred[0], sred[1]), fmaxf(sred[2], sred[3]));
        unsigned eb = __float_as_uint(m);
        eb = (eb & 0x80000000u) ? ~eb : (eb | 0x80000000u);
        atomicMax(slot, eb);
    }
}

template<int H>
__device__ void hfill_body(_Float16* __restrict__ inT, const float* __restrict__ hpre, int b)
{
    constexpr int HW = H * H;
    int idx = blockIdx.x * 256 + threadIdx.x;
    if (idx >= HW * 17) return;
    int c = 15 + idx / HW;
    int p2 = idx % HW;
    _Float16* base = inT + ((size_t)b * HW + p2) * 256 + c * 8;
    union { _Float16 h[8]; uint4 u; } d;
    if (c == 15) {
        d.u = *(const uint4*)base;
#pragma unroll
        for (int j = 1; j < 8; ++j)
            d.h[j] = (_Float16)hpre[((size_t)b * PP + (j - 1)) * HW + p2];
    } else if (c <= 29) {
#pragma unroll
        for (int j = 0; j < 8; ++j)
            d.h[j] = (_Float16)hpre[((size_t)b * PP + (c * 8 + j - 121)) * HW + p2];
    } else if (c == 30) {
        d.h[0] = (_Float16)hpre[((size_t)b * PP + 119) * HW + p2];
        d.h[1] = (_Float16)hpre[((size_t)b * PP + 120) * HW + p2];
#pragma unroll
        for (int j = 2; j < 8; ++j) d.h[j] = (_Float16)0.f;
    } else {
#pragma unroll
        for (int j = 0; j < 8; ++j) d.h[j] = (_Float16)0.f;
    }
    *(uint4*)base = d.u;
}

__global__ __launch_bounds__(256) void tiny_corr_kernel(
    TinyArgs ta, _Float16* __restrict__ inT, unsigned* __restrict__ slots)
{
    const int z = blockIdx.z, b = blockIdx.y;
    if      (z == 0) corr_small_body<8>(ta.x[0], ta.xp[0], inT,          slots + 3, b);
    else if (z == 1) corr_small_body<4>(ta.x[1], ta.xp[1], inT + 131072, slots + 4, b);
    else             corr_small_body<2>(ta.x[2], ta.xp[2], inT + 163840, slots + 5, b);
}

__global__ __launch_bounds__(256) void tiny_hfill_kernel(
    TinyArgs ta, _Float16* __restrict__ inT)
{
    const int z = blockIdx.z, b = blockIdx.y;
    if      (z == 0) hfill_body<8>(inT,          ta.h[0], b);
    else if (z == 1) hfill_body<4>(inT + 131072, ta.h[1], b);
    else             hfill_body<2>(inT + 163840, ta.h[2], b);
}

__global__ __launch_bounds__(256) void pack_tiny_kernel(
    TinyArgs ta, _Float16* __restrict__ a0, _Float16* __restrict__ a1,
    _Float16* __restrict__ a2, const unsigned* __restrict__ slots)
{
    __shared__ float sW[16 * 292];
    const int z = blockIdx.z;
    _Float16* Ap = (z == 0) ? a0 : (z == 1 ? a1 : a2);
    float inv = 1.0f / decode_max(slots + 3 + z);
    pack2_body(ta.w[z], Ap, inv, blockIdx.x >> 3, blockIdx.x & 7, threadIdx.x, sW);
}

// ---------------------------------------------------------------------------
// conv v3 (r13-verified dbuf structure) + s_setprio around MFMA clusters
// (zero VGPR cost; conv K-loop is barrier-free -> waves phase-diverse -> T5).
template<int H, int TR, int MSPLIT>
__global__ __launch_bounds__(512, 4) void conv_mfma3_kernel(
    const _Float16* __restrict__ inT, const float* __restrict__ cpre,
    const _Float16* __restrict__ Apack, const float* __restrict__ bias,
    const _Float16* __restrict__ zg,
    float* __restrict__ outh, float* __restrict__ outc)
{
    constexpr int W = H;
    constexpr int TC = 16, SR = TC + 2;
    constexpr int NPOS = (TR + 2) * SR;
    constexpr int MT_BLK = 32 / MSPLIT;
    constexpr int AF = 4 / MSPLIT;
    constexpr int TILES_X = W / TC;
    __shared__ _Float16 sIn[NPOS * 256];

    const int tid  = threadIdx.x;
    const int b    = blockIdx.y;
    const int mblk = blockIdx.z;
    const int tile = blockIdx.x;
    const int ty0  = (tile / TILES_X) * TR;
    const int tx0  = (tile % TILES_X) * TC;
    const int w = tid >> 6, lane = tid & 63;
    const int lcol = lane & 15, kg = lane >> 4;

    char* sB = (char*)sIn;
    for (int it = w; it < NPOS / 2; it += 8) {
        int r  = it * 2 + (lane >> 5);
        int c  = lane & 31;
        int iy = r / SR, ix = r % SR;
        int gy = ty0 + iy - 1, gx = tx0 + ix - 1;
        const void* src;
        if (gy >= 0 && gy < H && gx >= 0 && gx < W)
            src = inT + ((size_t)(b * H + gy) * W + gx) * 256 + (c ^ (ix & 7)) * 8;
        else
            src = zg + lane * 8;
        GLOAD16(src, sB + it * 1024);
    }
    __syncthreads();

    const int mtg0 = mblk * MT_BLK + w * AF;

    f32x4 acc[AF * TR];
#pragma unroll
    for (int a = 0; a < AF; ++a) {
        int q = (mtg0 + a) * 4 + kg;
        f32x4 bv;
#pragma unroll
        for (int r = 0; r < 4; ++r) bv[r] = (q < PP) ? bias[r * PP + q] : 0.f;
#pragma unroll
        for (int j = 0; j < TR; ++j) acc[a * TR + j] = bv;
    }

    const f16x8* apL = (const f16x8*)Apack + (size_t)mtg0 * 64 + lane;

    auto COMPUTE = [&](const f16x8* af, int s) {
        int k9 = s >> 3, ks = s & 7;
        int ky = k9 / 3, kx = k9 - ky * 3;
        int ix = lcol + kx;
        int xsw = (ix & 7) << 4;
        int cb  = kg * 16 + ks * 64;
        __builtin_amdgcn_s_setprio(1);
#pragma unroll
        for (int j = 0; j < TR; ++j) {
            int addr = ((((j + ky) * SR + ix) * 512) + cb) ^ xsw;
            f16x8 bf = *(const f16x8*)(sB + addr);
#pragma unroll
            for (int a = 0; a < AF; ++a)
                acc[a * TR + j] = __builtin_amdgcn_mfma_f32_16x16x32_f16(af[a], bf, acc[a * TR + j], 0, 0, 0);
        }
        __builtin_amdgcn_s_setprio(0);
    };

    f16x8 afA[AF], afB[AF];
#pragma unroll
    for (int a = 0; a < AF; ++a) afA[a] = apL[a * 64];
#pragma unroll 1
    for (int s2 = 0; s2 < 36; ++s2) {
        const f16x8* apB = apL + (size_t)(s2 * 2 + 1) * 2048;
#pragma unroll
        for (int a = 0; a < AF; ++a) afB[a] = apB[a * 64];
        COMPUTE(afA, s2 * 2);
        if (s2 < 35) {
            const f16x8* apA = apL + (size_t)(s2 * 2 + 2) * 2048;
#pragma unroll
            for (int a = 0; a < AF; ++a) afA[a] = apA[a * 64];
        }
        COMPUTE(afB, s2 * 2 + 1);
    }

#pragma unroll
    for (int a = 0; a < AF; ++a) {
        int q = (mtg0 + a) * 4 + kg;
        if (q >= PP) continue;
#pragma unroll
        for (int j = 0; j < TR; ++j) {
            int y = ty0 + j, x = tx0 + lcol;
            if (y >= H) continue;
            float ai = acc[a * TR + j][0];
            float af_ = acc[a * TR + j][1];
            float ao = acc[a * TR + j][2];
            float ag = acc[a * TR + j][3];
            float ig = 1.f / (1.f + expf(-ai));
            float fg = 1.f / (1.f + expf(-af_));
            float og = 1.f / (1.f + expf(-ao));
            float gg = tanhf(ag);
            size_t oidx = (((size_t)b * PP + q) * H + y) * W + x;
            float cp = cpre[oidx];
            float cn = fg * cp + ig * gg;
            outh[oidx] = og * tanhf(cn);
            outc[oidx] = cn;
        }
    }
}

// ---------------------------------------------------------------------------
// batched tiny conv: whole image per block, M-split over blockIdx.x, level
// over blockIdx.z.
template<int H>
__device__ void conv_tiny_body(const _Float16* __restrict__ inT,
    const float* __restrict__ cpre, const _Float16* __restrict__ Apack,
    const float* __restrict__ bias, float* __restrict__ outh,
    float* __restrict__ outc, int b, int mblk, char* __restrict__ sB)
{
    constexpr int NPX = H * H;
    constexpr int NT  = (NPX + 15) / 16;
    constexpr int SR  = H + 2;
    constexpr int NPOS = SR * SR;
    const int tid = threadIdx.x;

    constexpr int CHUNKS = NPOS * 32;
    for (int flat = tid; flat < CHUNKS; flat += 512) {
        int cg  = flat & 31;
        int pos = flat >> 5;
        int iy = pos / SR, ix = pos % SR;
        int gy = iy - 1, gx = ix - 1;
        f16x8 v = {0, 0, 0, 0, 0, 0, 0, 0};
        if (gy >= 0 && gy < H && gx >= 0 && gx < H)
            v = *(const f16x8*)(inT + ((size_t)(b * H + gy) * H + gx) * 256 + cg * 8);
        int dst = (pos * 512 + cg * 16) ^ ((ix & 7) << 4);
        *(f16x8*)(sB + dst) = v;
    }
    __syncthreads();

    const int w = tid >> 6, lane = tid & 63;
    const int lcol = lane & 15, kg = lane >> 4;
    const int mt = mblk * 8 + w;
    const int q  = mt * 4 + kg;

    f32x4 acc[NT];
    f32x4 bv;
#pragma unroll
    for (int r = 0; r < 4; ++r) bv[r] = (q < PP) ? bias[r * PP + q] : 0.f;
#pragma unroll
    for (int nt = 0; nt < NT; ++nt) acc[nt] = bv;

#pragma unroll 1
    for (int k9 = 0; k9 < 9; ++k9) {
        const int ky = k9 / 3, kx = k9 % 3;
        int basev[NT], xswv[NT];
#pragma unroll
        for (int nt = 0; nt < NT; ++nt) {
            int p = nt * 16 + lcol;
            int pc = (NPX < 16 && p >= NPX) ? 0 : p;
            int py = pc / H, px = pc % H;
            int iy = py + ky, ix = px + kx;
            basev[nt] = (iy * SR + ix) * 512 + kg * 16;
            xswv[nt]  = (ix & 7) << 4;
        }
        const f16x8* apb = (const f16x8*)Apack + ((size_t)(k9 * 8) * 32 + mt) * 64 + lane;
#pragma unroll 1
        for (int ks = 0; ks < 8; ++ks) {
            f16x8 bf[NT];
#pragma unroll
            for (int nt = 0; nt < NT; ++nt) {
                bf[nt] = *(const f16x8*)(sB + ((basev[nt] + ks * 64) ^ xswv[nt]));
                if (NPX < 16 && nt * 16 + lcol >= NPX) bf[nt] = (f16x8){};
            }
            f16x8 af = apb[(size_t)ks * 32 * 64];
#pragma unroll
            for (int nt = 0; nt < NT; ++nt)
                acc[nt] = __builtin_amdgcn_mfma_f32_16x16x32_f16(af, bf[nt], acc[nt], 0, 0, 0);
        }
    }

    if (q < PP) {
#pragma unroll
        for (int nt = 0; nt < NT; ++nt) {
            int p = nt * 16 + lcol;
            if (NPX < 16 && p >= NPX) continue;
            int py = p / H, px = p % H;
            float ai = acc[nt][0];
            float af_ = acc[nt][1];
            float ao = acc[nt][2];
            float ag = acc[nt][3];
            float ig = 1.f / (1.f + expf(-ai));
            float fg = 1.f / (1.f + expf(-af_));
            float og = 1.f / (1.f + expf(-ao));
            float gg = tanhf(ag);
            size_t oidx = (((size_t)b * PP + q) * H + py) * H + px;
            float cp = cpre[oidx];
            float cn = fg * cp + ig * gg;
            outh[oidx] = og * tanhf(cn);
            outc[oidx] = cn;
        }
    }
}

__global__ __launch_bounds__(512, 4) void conv_tiny_kernel(
    TinyArgs ta, const _Float16* __restrict__ inT,
    const _Float16* __restrict__ a0, const _Float16* __restrict__ a1,
    const _Float16* __restrict__ a2)
{
    __shared__ char sB[100 * 512];
    const int z = blockIdx.z, b = blockIdx.y, mblk = blockIdx.x;
    if      (z == 0) conv_tiny_body<8>(inT,          ta.c[0], a0, ta.bi[0], ta.oh[0], ta.oc[0], b, mblk, sB);
    else if (z == 1) conv_tiny_body<4>(inT + 131072, ta.c[1], a1, ta.bi[1], ta.oh[1], ta.oc[1], b, mblk, sB);
    else             conv_tiny_body<2>(inT + 163840, ta.c[2], a2, ta.bi[2], ta.oh[2], ta.oc[2], b, mblk, sB);
}

// ---------------------------------------------------------------------------
extern "C" void kernel_launch(void* const* d_in, const int* in_sizes, int n_in,
                              void* d_out, int out_size, void* d_ws, size_t ws_size,
                              hipStream_t stream) {
    (void)in_sizes; (void)n_in; (void)out_size; (void)ws_size;
    static const int HH[6] = {64, 32, 16, 8, 4, 2};

    unsigned* maxslots = (unsigned*)d_ws;
    _Float16* Apack = (_Float16*)((char*)d_ws + 256);
    _Float16* inT   = (_Float16*)((char*)d_ws + 2359808);
    _Float16* xT    = (_Float16*)((char*)d_ws + 19137024);
    _Float16* xpT   = (_Float16*)((char*)d_ws + 52691456);
    _Float16* zg    = (_Float16*)((char*)d_ws + 86245888);
    _Float16* apT0 = (_Float16*)((char*)d_ws + 19137024);
    _Float16* apT1 = (_Float16*)((char*)d_ws + 19137024 + 2359296);
    _Float16* apT2 = (_Float16*)((char*)d_ws + 19137024 + 2 * 2359296);

    float* out = (float*)d_out;
    size_t obase[6];
    {
        size_t ob = 0;
        for (int L = 0; L < 6; ++L) { obase[L] = ob; ob += 2ull * NB * PP * HH[L] * HH[L]; }
    }

    init_kernel<<<1, 256, 0, stream>>>(maxslots, (float*)zg);

    // ---- big levels 0..2 ----
    for (int L = 0; L < 3; ++L) {
        const float* x    = (const float*)d_in[6 * L + 0];
        const float* xp   = (const float*)d_in[6 * L + 1];
        const float* h    = (const float*)d_in[6 * L + 2];
        const float* c    = (const float*)d_in[6 * L + 3];
        const float* Wsrc = (const float*)d_in[6 * L + 4];
        const float* bias = (const float*)d_in[6 * L + 5];
        int Hh = HH[L];
        int S = NB * PP * Hh * Hh;
        float* oh = out + obase[L];
        float* oc = out + obase[L] + S;

        switch (L) {
            case 0:
                tpose_kernel<512, 64, 32><<<dim3(16, NB * 64, 2), 256, 0, stream>>>(x, xp, xT, xpT);
                corr_mfma_kernel<512, 64, 8, 8><<<dim3(64, NB), 512, 0, stream>>>(xT, xpT, zg, inT, maxslots + 0);
                post_kernel<64><<<256 + (NB * 64 * 64 * 17 + 255) / 256, 256, 0, stream>>>(inT, h, Wsrc, Apack, maxslots + 0);
                conv_mfma3_kernel<64, 4, 1><<<dim3(64, 8, 1), 512, 0, stream>>>(inT, c, Apack, bias, zg, oh, oc);
                break;
            case 1:
                tpose_kernel<1024, 32, 32><<<dim3(16, NB * 32, 2), 256, 0, stream>>>(x, xp, xT, xpT);
                corr_mfma_kernel<1024, 32, 4, 8><<<dim3(32, NB), 512, 0, stream>>>(xT, xpT, zg, inT, maxslots + 1);
                post_kernel<32><<<256 + (NB * 32 * 32 * 17 + 255) / 256, 256, 0, stream>>>(inT, h, Wsrc, Apack, maxslots + 1);
                conv_mfma3_kernel<32, 4, 2><<<dim3(16, 8, 2), 512, 0, stream>>>(inT, c, Apack, bias, zg, oh, oc);
                break;
            case 2:
                tpose_kernel<512, 16, 16><<<dim3(8, NB * 16, 2), 256, 0, stream>>>(x, xp, xT, xpT);
                corr_mfma_kernel<512, 16, 4, 4><<<dim3(16, NB), 512, 0, stream>>>(xT, xpT, zg, inT, maxslots + 2);
                post_kernel<16><<<256 + (NB * 16 * 16 * 17 + 255) / 256, 256, 0, stream>>>(inT, h, Wsrc, Apack, maxslots + 2);
                conv_mfma3_kernel<16, 4, 4><<<dim3(4, 8, 4), 512, 0, stream>>>(inT, c, Apack, bias, zg, oh, oc);
                break;
        }
    }

    // ---- tiny levels 3..5, batched ----
    TinyArgs ta;
    for (int i = 0; i < 3; ++i) {
        int L = 3 + i;
        ta.x[i]  = (const float*)d_in[6 * L + 0];
        ta.xp[i] = (const float*)d_in[6 * L + 1];
        ta.h[i]  = (const float*)d_in[6 * L + 2];
        ta.c[i]  = (const float*)d_in[6 * L + 3];
        ta.w[i]  = (const float*)d_in[6 * L + 4];
        ta.bi[i] = (const float*)d_in[6 * L + 5];
        int S = NB * PP * HH[L] * HH[L];
        ta.oh[i] = out + obase[L];
        ta.oc[i] = out + obase[L] + S;
    }
    tiny_corr_kernel<<<dim3(31, NB, 3), 256, 0, stream>>>(ta, inT, maxslots);
    tiny_hfill_kernel<<<dim3(5, NB, 3), 256, 0, stream>>>(ta, inT);
    pack_tiny_kernel<<<dim3(256, 1, 3), 256, 0, stream>>>(ta, apT0, apT1, apT2, maxslots);
    conv_tiny_kernel<<<dim3(4, NB, 3), 512, 0, stream>>>(ta, inT, apT0, apT1, apT2);
}

// Round 16
// 352.825 us; speedup vs baseline: 1.1696x; 1.0855x over previous
//
#include <hip/hip_runtime.h>
#include <hip/hip_bf16.h>
#include <cstdint>
#include <cstddef>

#define PD 11
#define PP 121
#define NB 8

typedef _Float16 f16x8 __attribute__((ext_vector_type(8)));
typedef float    f32x4 __attribute__((ext_vector_type(4)));

#define GLOAD16(SRC, DST) __builtin_amdgcn_global_load_lds( \
    (const __attribute__((address_space(1))) void*)(SRC),   \
    (__attribute__((address_space(3))) void*)(DST), 16, 0, 0)

struct TinyArgs {
    const float* x[3]; const float* xp[3]; const float* h[3];
    const float* c[3]; const float* w[3]; const float* bi[3];
    float* oh[3]; float* oc[3];
};

struct ConvArgs {
    const _Float16 *inT0, *inT1, *inT2;
    const float *c0, *c1, *c2;
    const _Float16 *ap0, *ap1, *ap2;
    const float *bi0, *bi1, *bi2;
    float *oh0, *oc0, *oh1, *oc1, *oh2, *oc2;
    const _Float16* zg;
};

// ---------------------------------------------------------------------------
__global__ void init_kernel(unsigned* __restrict__ slots, float* __restrict__ zg) {
    int t = threadIdx.x;
    if (t < 8) slots[t] = 0x007FFFFFu;  // enc(-inf)
    for (int i = t; i < 1024; i += 256) zg[i] = 0.f;
}

__device__ __forceinline__ float decode_max(const unsigned* slot) {
    unsigned mu = *slot;
    return (mu & 0x80000000u) ? __uint_as_float(mu ^ 0x80000000u) : __uint_as_float(~mu);
}

// ---------------------------------------------------------------------------
// fused fp32 NCHW -> fp16 NHWC transpose for x AND xp (blockIdx.z selects).
template<int C, int H, int TPX>
__global__ __launch_bounds__(256) void tpose_kernel(
    const float* __restrict__ xin, const float* __restrict__ xpin,
    _Float16* __restrict__ xT, _Float16* __restrict__ xpT)
{
    constexpr int W = H;
    const float* in  = blockIdx.z ? xpin : xin;
    _Float16*   out  = blockIdx.z ? xpT  : xT;
    const int by = blockIdx.y;
    const int b  = by / H, y = by % H;
    constexpr int NXT = W / TPX;
    const int x0 = (blockIdx.x % NXT) * TPX;
    const int cc = (blockIdx.x / NXT) * 64;
    __shared__ float s[64][36];

    constexpr int NF4 = 64 * TPX / 4;
    for (int f = threadIdx.x; f < NF4; f += 256) {
        int r  = f / (TPX / 4);
        int xq = f % (TPX / 4);
        int col = (xq * 4) ^ (((r >> 3) & 7) * 4);
        *(float4*)&s[r][col] =
            *(const float4*)&in[((size_t)(b * C + cc + r) * H + y) * W + x0 + xq * 4];
    }
    __syncthreads();
    constexpr int NWT = TPX * 8;
    for (int t = threadIdx.x; t < NWT; t += 256) {
        int pix = t >> 3, ck = t & 7;
        union { _Float16 h[8]; f16x8 v; } d;
#pragma unroll
        for (int j = 0; j < 8; ++j)
            d.h[j] = (_Float16)s[ck * 8 + j][pix ^ (ck * 4)];
        *(f16x8*)&out[((size_t)(b * H + y) * W + x0 + pix) * C + cc + ck * 8] = d.v;
    }
}

// ---------------------------------------------------------------------------
// MFMA correlation, double-buffered gload_lds staging. RAW leaky'd corr ->
// inT channels [0,128) + block max -> atomicMax.
template<int C, int H, int TSY, int TSX>
__global__ __launch_bounds__(512, 2) void corr_mfma_kernel(
    const _Float16* __restrict__ xT, const _Float16* __restrict__ xpT,
    const _Float16* __restrict__ zg,
    _Float16* __restrict__ inT, unsigned* __restrict__ slot)
{
    constexpr int W  = H;
    constexpr int HY = TSY + 10, HX = TSX + 10;
    constexpr int MZ = HY * HX;
    constexpr int MT = (MZ + 15) / 16;
    constexpr int MTP = MT * 16;
    constexpr int MFRAG = (MT + 7) / 8;
    constexpr int NPX = TSY * TSX;
    constexpr int NT  = NPX / 16;
    constexpr int KC  = C / 32;
    constexpr int ABYTES = MTP * 64;
    constexpr int BUF    = ABYTES + NPX * 64;
    constexpr int NLOAD  = BUF / 1024;
    constexpr int ST2    = NPX + 8;
    constexpr int ST_B   = MTP * ST2 * 2;
    constexpr int LDS_B  = (2 * BUF > ST_B) ? 2 * BUF : ST_B;
    __shared__ char smem[LDS_B];
    __shared__ float sred[8];

    const int tid  = threadIdx.x;
    const int b    = blockIdx.y;
    constexpr int TXT = W / TSX;
    const int y0 = (blockIdx.x / TXT) * TSY;
    const int x0 = (blockIdx.x % TXT) * TSX;
    const int w = tid >> 6, lane = tid & 63;
    const int lcol = lane & 15, lkg = lane >> 4;

    auto STAGE = [&](int bufsel, int kc) {
        char* dstb = smem + bufsel * BUF;
        int c = lane & 3;
        for (int it = w; it < NLOAD; it += 8) {
            const void* src;
            if (it < MTP / 16) {
                int z = it * 16 + (lane >> 2);
                int zy = y0 + z / HX - 5, zx = x0 + z % HX - 5;
                if (z < MZ && zy >= 0 && zy < H && zx >= 0 && zx < W)
                    src = xpT + ((size_t)(b * H + zy) * W + zx) * C + kc * 32 + ((c ^ (z >> 2)) & 3) * 8;
                else
                    src = zg + lane * 8;
            } else {
                int p = (it - MTP / 16) * 16 + (lane >> 2);
                int gy = y0 + p / TSX, gx = x0 + p % TSX;
                src = xT + ((size_t)(b * H + gy) * W + gx) * C + kc * 32 + ((c ^ (p >> 2)) & 3) * 8;
            }
            GLOAD16(src, dstb + it * 1024);
        }
    };

    f32x4 acc[MFRAG][NT];
#pragma unroll
    for (int i = 0; i < MFRAG; ++i)
#pragma unroll
        for (int nt = 0; nt < NT; ++nt)
            acc[i][nt] = (f32x4){0.f, 0.f, 0.f, 0.f};

    STAGE(0, 0);
    __syncthreads();
#pragma unroll 1
    for (int kc = 0; kc < KC; ++kc) {
        if (kc + 1 < KC) STAGE((kc + 1) & 1, kc + 1);
        const char* bb = smem + (kc & 1) * BUF;
        f16x8 bF[NT];
#pragma unroll
        for (int nt = 0; nt < NT; ++nt) {
            int p = nt * 16 + lcol;
            bF[nt] = *(const f16x8*)(bb + ABYTES + p * 64 + (((lkg ^ (p >> 2)) & 3) << 4));
        }
#pragma unroll
        for (int i = 0; i < MFRAG; ++i) {
            int mt = w + i * 8;
            if (mt < MT) {
                int z = mt * 16 + lcol;
                f16x8 aF = *(const f16x8*)(bb + z * 64 + (((lkg ^ (z >> 2)) & 3) << 4));
#pragma unroll
                for (int nt = 0; nt < NT; ++nt)
                    acc[i][nt] = __builtin_amdgcn_mfma_f32_16x16x32_f16(aF, bF[nt], acc[i][nt], 0, 0, 0);
            }
        }
        __syncthreads();
    }

    _Float16* sT = (_Float16*)smem;
#pragma unroll
    for (int i = 0; i < MFRAG; ++i) {
        int mt = w + i * 8;
        if (mt >= MT) continue;
        int z0 = mt * 16 + lkg * 4;
#pragma unroll
        for (int nt = 0; nt < NT; ++nt) {
            int p = nt * 16 + lcol;
#pragma unroll
            for (int r = 0; r < 4; ++r)
                sT[(z0 + r) * ST2 + p] = (_Float16)acc[i][nt][r];
        }
    }
    __syncthreads();

    float lmax = -3.4e38f;
    if (tid < NPX * 8) {
        int p  = tid >> 3;
        int qg = tid & 7;
        int py = p / TSX, px = p % TSX;
        size_t pix = (size_t)(b * H + y0 + py) * W + (x0 + px);
        unsigned* dst = (unsigned*)(inT + pix * 256) + qg * 8;
#pragma unroll
        for (int j2 = 0; j2 < 8; ++j2) {
            int q0 = qg * 16 + j2 * 2, q1 = q0 + 1;
            int qc0 = q0 < PP ? q0 : PP - 1;
            int qc1 = q1 < PP ? q1 : PP - 1;
            float v0 = (float)sT[((py + qc0 / PD) * HX + (px + qc0 % PD)) * ST2 + p];
            float v1 = (float)sT[((py + qc1 / PD) * HX + (px + qc1 % PD)) * ST2 + p];
            v0 = v0 > 0.f ? v0 : 0.01f * v0;
            v1 = v1 > 0.f ? v1 : 0.01f * v1;
            if (q0 < PP) lmax = fmaxf(lmax, v0);
            if (q1 < PP) lmax = fmaxf(lmax, v1);
            union { _Float16 h[2]; unsigned u; } pk;
            pk.h[0] = (_Float16)v0; pk.h[1] = (_Float16)v1;
            dst[j2] = pk.u;
        }
    }
    for (int off = 32; off; off >>= 1) lmax = fmaxf(lmax, __shfl_down(lmax, off));
    if (lane == 0) sred[w] = lmax;
    __syncthreads();
    if (tid == 0) {
        float m = sred[0];
        for (int i = 1; i < 8; ++i) m = fmaxf(m, sred[i]);
        unsigned eb = __float_as_uint(m);
        eb = (eb & 0x80000000u) ? ~eb : (eb | 0x80000000u);
        atomicMax(slot, eb);
    }
}

// ---------------------------------------------------------------------------
// coalesced weight pack body (LDS-staged, u32 fragment writes, prescale).
__device__ __forceinline__ void pack2_body(
    const float* __restrict__ Wsrc, _Float16* __restrict__ Apack,
    float inv, int mt, int ks, int tid, float* __restrict__ sW)
{
    const int icmax9 = (242 - ks * 32) * 9;
    for (int f = tid; f < 16 * 288; f += 256) {
        int r = f / 288, i = f - r * 288;
        int m = mt * 16 + r;
        float v = 0.f;
        if (m < 484 && i < icmax9) {
            int q = m >> 2, g = m & 3;
            v = Wsrc[((size_t)(g * PP + q) * 242 + ks * 32) * 9 + i];
        }
        sW[r * 292 + i] = v;
    }
    __syncthreads();
    const int o = tid * 2;
    const int l = o >> 3, e0 = o & 7;
    const int r = l & 15;
    const int klbase = (l >> 4) * 8;
    const int ic0 = ks * 32 + klbase + e0;
#pragma unroll 1
    for (int k9 = 0; k9 < 9; ++k9) {
        float v0 = sW[r * 292 + (klbase + e0) * 9 + k9];
        float v1 = sW[r * 292 + (klbase + e0 + 1) * 9 + k9];
        if (ic0 < PP)     v0 *= inv;
        if (ic0 + 1 < PP) v1 *= inv;
        union { _Float16 h[2]; unsigned u; } pk;
        pk.h[0] = (_Float16)v0; pk.h[1] = (_Float16)v1;
        *(unsigned*)((char*)Apack + (size_t)((k9 * 8 + ks) * 32 + mt) * 1024 + o * 2) = pk.u;
    }
}

// ---------------------------------------------------------------------------
// merged post-corr kernel for big levels: blocks [0,256) = pack, rest = h-fill.
template<int H>
__global__ __launch_bounds__(256) void post_kernel(
    _Float16* __restrict__ inT, const float* __restrict__ hpre,
    const float* __restrict__ Wsrc, _Float16* __restrict__ Apack,
    const unsigned* __restrict__ slot)
{
    __shared__ float sW[16 * 292];
    const int bx = blockIdx.x, tid = threadIdx.x;
    if (bx < 256) {
        float inv = 1.0f / decode_max(slot);
        pack2_body(Wsrc, Apack, inv, bx >> 3, bx & 7, tid, sW);
        return;
    }
    constexpr int HW = H * H;
    constexpr int NP = NB * HW;
    int idx = (bx - 256) * 256 + tid;
    if (idx >= NP * 17) return;
    int c = 15 + idx / NP;
    int pix = idx % NP;
    int b = pix / HW, p2 = pix % HW;
    _Float16* base = inT + (size_t)pix * 256 + c * 8;
    union { _Float16 h[8]; uint4 u; } d;
    if (c == 15) {
        d.u = *(const uint4*)base;
#pragma unroll
        for (int j = 1; j < 8; ++j)
            d.h[j] = (_Float16)hpre[((size_t)b * PP + (j - 1)) * HW + p2];
    } else if (c <= 29) {
#pragma unroll
        for (int j = 0; j < 8; ++j)
            d.h[j] = (_Float16)hpre[((size_t)b * PP + (c * 8 + j - 121)) * HW + p2];
    } else if (c == 30) {
        d.h[0] = (_Float16)hpre[((size_t)b * PP + 119) * HW + p2];
        d.h[1] = (_Float16)hpre[((size_t)b * PP + 120) * HW + p2];
#pragma unroll
        for (int j = 2; j < 8; ++j) d.h[j] = (_Float16)0.f;
    } else {
#pragma unroll
        for (int j = 0; j < 8; ++j) d.h[j] = (_Float16)0.f;
    }
    *(uint4*)base = d.u;
}

// ---------------------------------------------------------------------------
// tiny levels (H=8/4/2): corr and h-fill in SEPARATE launches.
template<int H>
__device__ void corr_small_body(const float* __restrict__ x, const float* __restrict__ xp,
    _Float16* __restrict__ inT, unsigned* __restrict__ slot, int b)
{
    constexpr int PX  = H * H;
    constexpr int TOT = PX * PP;
    const int o = blockIdx.x * 256 + threadIdx.x;
    float v = -3.4e38f;
    if (o < TOT) {
        int p = o / PP;
        int q = o - p * PP;
        int y = p / H, xx = p % H;
        int sy = y + q / PD - 5, sx = xx + q % PD - 5;
        float acc = 0.f;
        if (sy >= 0 && sy < H && sx >= 0 && sx < H) {
            const float* xb  = x  + (size_t)b * 256 * PX + p;
            const float* xpb = xp + (size_t)b * 256 * PX + sy * H + sx;
#pragma unroll 8
            for (int c = 0; c < 256; ++c)
                acc = fmaf(xb[c * PX], xpb[c * PX], acc);
        }
        float lv = acc > 0.f ? acc : 0.01f * acc;
        inT[((size_t)b * PX + p) * 256 + q] = (_Float16)lv;
        v = lv;
    }
    for (int off = 32; off; off >>= 1) v = fmaxf(v, __shfl_down(v, off));
    __shared__ float sred[4];
    if ((threadIdx.x & 63) == 0) sred[threadIdx.x >> 6] = v;
    __syncthreads();
    if (threadIdx.x == 0) {
        float m = fmaxf(fmaxf(sred[0], sred[1]), fmaxf(sred[2], sred[3]));
        unsigned eb = __float_as_uint(m);
        eb = (eb & 0x80000000u) ? ~eb : (eb | 0x80000000u);
        atomicMax(slot, eb);
    }
}

template<int H>
__device__ void hfill_body(_Float16* __restrict__ inT, const float* __restrict__ hpre, int b)
{
    constexpr int HW = H * H;
    int idx = blockIdx.x * 256 + threadIdx.x;
    if (idx >= HW * 17) return;
    int c = 15 + idx / HW;
    int p2 = idx % HW;
    _Float16* base = inT + ((size_t)b * HW + p2) * 256 + c * 8;
    union { _Float16 h[8]; uint4 u; } d;
    if (c == 15) {
        d.u = *(const uint4*)base;
#pragma unroll
        for (int j = 1; j < 8; ++j)
            d.h[j] = (_Float16)hpre[((size_t)b * PP + (j - 1)) * HW + p2];
    } else if (c <= 29) {
#pragma unroll
        for (int j = 0; j < 8; ++j)
            d.h[j] = (_Float16)hpre[((size_t)b * PP + (c * 8 + j - 121)) * HW + p2];
    } else if (c == 30) {
        d.h[0] = (_Float16)hpre[((size_t)b * PP + 119) * HW + p2];
        d.h[1] = (_Float16)hpre[((size_t)b * PP + 120) * HW + p2];
#pragma unroll
        for (int j = 2; j < 8; ++j) d.h[j] = (_Float16)0.f;
    } else {
#pragma unroll
        for (int j = 0; j < 8; ++j) d.h[j] = (_Float16)0.f;
    }
    *(uint4*)base = d.u;
}

__global__ __launch_bounds__(256) void tiny_corr_kernel(
    TinyArgs ta, _Float16* __restrict__ inT, unsigned* __restrict__ slots)
{
    const int z = blockIdx.z, b = blockIdx.y;
    if      (z == 0) corr_small_body<8>(ta.x[0], ta.xp[0], inT,          slots + 3, b);
    else if (z == 1) corr_small_body<4>(ta.x[1], ta.xp[1], inT + 131072, slots + 4, b);
    else             corr_small_body<2>(ta.x[2], ta.xp[2], inT + 163840, slots + 5, b);
}

__global__ __launch_bounds__(256) void tiny_hfill_kernel(
    TinyArgs ta, _Float16* __restrict__ inT)
{
    const int z = blockIdx.z, b = blockIdx.y;
    if      (z == 0) hfill_body<8>(inT,          ta.h[0], b);
    else if (z == 1) hfill_body<4>(inT + 131072, ta.h[1], b);
    else             hfill_body<2>(inT + 163840, ta.h[2], b);
}

__global__ __launch_bounds__(256) void pack_tiny_kernel(
    TinyArgs ta, _Float16* __restrict__ a0, _Float16* __restrict__ a1,
    _Float16* __restrict__ a2, const unsigned* __restrict__ slots)
{
    __shared__ float sW[16 * 292];
    const int z = blockIdx.z;
    _Float16* Ap = (z == 0) ? a0 : (z == 1 ? a1 : a2);
    float inv = 1.0f / decode_max(slots + 3 + z);
    pack2_body(ta.w[z], Ap, inv, blockIdx.x >> 3, blockIdx.x & 7, threadIdx.x, sW);
}

// ---------------------------------------------------------------------------
// conv v3 body (r15-verified): TR x 16 tile, gload_lds staging, A-frag
// register double-buffer, setprio around MFMA clusters.
template<int H, int TR, int MSPLIT>
__device__ void conv_mfma3_body(
    const _Float16* __restrict__ inT, const float* __restrict__ cpre,
    const _Float16* __restrict__ Apack, const float* __restrict__ bias,
    const _Float16* __restrict__ zg,
    float* __restrict__ outh, float* __restrict__ outc,
    int tile, int b, int mblk, char* __restrict__ sB)
{
    constexpr int W = H;
    constexpr int TC = 16, SR = TC + 2;
    constexpr int NPOS = (TR + 2) * SR;
    constexpr int MT_BLK = 32 / MSPLIT;
    constexpr int AF = 4 / MSPLIT;
    constexpr int TILES_X = W / TC;

    const int tid  = threadIdx.x;
    const int ty0  = (tile / TILES_X) * TR;
    const int tx0  = (tile % TILES_X) * TC;
    const int w = tid >> 6, lane = tid & 63;
    const int lcol = lane & 15, kg = lane >> 4;

    for (int it = w; it < NPOS / 2; it += 8) {
        int r  = it * 2 + (lane >> 5);
        int c  = lane & 31;
        int iy = r / SR, ix = r % SR;
        int gy = ty0 + iy - 1, gx = tx0 + ix - 1;
        const void* src;
        if (gy >= 0 && gy < H && gx >= 0 && gx < W)
            src = inT + ((size_t)(b * H + gy) * W + gx) * 256 + (c ^ (ix & 7)) * 8;
        else
            src = zg + lane * 8;
        GLOAD16(src, sB + it * 1024);
    }
    __syncthreads();

    const int mtg0 = mblk * MT_BLK + w * AF;

    f32x4 acc[AF * TR];
#pragma unroll
    for (int a = 0; a < AF; ++a) {
        int q = (mtg0 + a) * 4 + kg;
        f32x4 bv;
#pragma unroll
        for (int r = 0; r < 4; ++r) bv[r] = (q < PP) ? bias[r * PP + q] : 0.f;
#pragma unroll
        for (int j = 0; j < TR; ++j) acc[a * TR + j] = bv;
    }

    const f16x8* apL = (const f16x8*)Apack + (size_t)mtg0 * 64 + lane;

    auto COMPUTE = [&](const f16x8* af, int s) {
        int k9 = s >> 3, ks = s & 7;
        int ky = k9 / 3, kx = k9 - ky * 3;
        int ix = lcol + kx;
        int xsw = (ix & 7) << 4;
        int cb  = kg * 16 + ks * 64;
        __builtin_amdgcn_s_setprio(1);
#pragma unroll
        for (int j = 0; j < TR; ++j) {
            int addr = ((((j + ky) * SR + ix) * 512) + cb) ^ xsw;
            f16x8 bf = *(const f16x8*)(sB + addr);
#pragma unroll
            for (int a = 0; a < AF; ++a)
                acc[a * TR + j] = __builtin_amdgcn_mfma_f32_16x16x32_f16(af[a], bf, acc[a * TR + j], 0, 0, 0);
        }
        __builtin_amdgcn_s_setprio(0);
    };

    f16x8 afA[AF], afB[AF];
#pragma unroll
    for (int a = 0; a < AF; ++a) afA[a] = apL[a * 64];
#pragma unroll 1
    for (int s2 = 0; s2 < 36; ++s2) {
        const f16x8* apB = apL + (size_t)(s2 * 2 + 1) * 2048;
#pragma unroll
        for (int a = 0; a < AF; ++a) afB[a] = apB[a * 64];
        COMPUTE(afA, s2 * 2);
        if (s2 < 35) {
            const f16x8* apA = apL + (size_t)(s2 * 2 + 2) * 2048;
#pragma unroll
            for (int a = 0; a < AF; ++a) afA[a] = apA[a * 64];
        }
        COMPUTE(afB, s2 * 2 + 1);
    }

#pragma unroll
    for (int a = 0; a < AF; ++a) {
        int q = (mtg0 + a) * 4 + kg;
        if (q >= PP) continue;
#pragma unroll
        for (int j = 0; j < TR; ++j) {
            int y = ty0 + j, x = tx0 + lcol;
            if (y >= H) continue;
            float ai = acc[a * TR + j][0];
            float af_ = acc[a * TR + j][1];
            float ao = acc[a * TR + j][2];
            float ag = acc[a * TR + j][3];
            float ig = 1.f / (1.f + expf(-ai));
            float fg = 1.f / (1.f + expf(-af_));
            float og = 1.f / (1.f + expf(-ao));
            float gg = tanhf(ag);
            size_t oidx = (((size_t)b * PP + q) * H + y) * W + x;
            float cp = cpre[oidx];
            float cn = fg * cp + ig * gg;
            outh[oidx] = og * tanhf(cn);
            outc[oidx] = cn;
        }
    }
}

// batched big-level conv: 896 blocks = 512 (L0) + 256 (L1) + 128 (L2).
__global__ __launch_bounds__(512, 4) void conv_all_kernel(ConvArgs ca)
{
    __shared__ char sB[108 * 512];   // 55296 B (max over levels, TR=4)
    const int bx = blockIdx.x;
    if (bx < 512) {
        conv_mfma3_body<64, 4, 1>(ca.inT0, ca.c0, ca.ap0, ca.bi0, ca.zg,
                                  ca.oh0, ca.oc0, bx & 63, bx >> 6, 0, sB);
    } else if (bx < 768) {
        int i = bx - 512;
        conv_mfma3_body<32, 4, 2>(ca.inT1, ca.c1, ca.ap1, ca.bi1, ca.zg,
                                  ca.oh1, ca.oc1, i & 15, (i >> 4) & 7, i >> 7, sB);
    } else {
        int i = bx - 768;
        conv_mfma3_body<16, 4, 4>(ca.inT2, ca.c2, ca.ap2, ca.bi2, ca.zg,
                                  ca.oh2, ca.oc2, i & 3, (i >> 2) & 7, i >> 5, sB);
    }
}

// ---------------------------------------------------------------------------
// batched tiny conv (unchanged from r15)
template<int H>
__device__ void conv_tiny_body(const _Float16* __restrict__ inT,
    const float* __restrict__ cpre, const _Float16* __restrict__ Apack,
    const float* __restrict__ bias, float* __restrict__ outh,
    float* __restrict__ outc, int b, int mblk, char* __restrict__ sB)
{
    constexpr int NPX = H * H;
    constexpr int NT  = (NPX + 15) / 16;
    constexpr int SR  = H + 2;
    constexpr int NPOS = SR * SR;
    const int tid = threadIdx.x;

    constexpr int CHUNKS = NPOS * 32;
    for (int flat = tid; flat < CHUNKS; flat += 512) {
        int cg  = flat & 31;
        int pos = flat >> 5;
        int iy = pos / SR, ix = pos % SR;
        int gy = iy - 1, gx = ix - 1;
        f16x8 v = {0, 0, 0, 0, 0, 0, 0, 0};
        if (gy >= 0 && gy < H && gx >= 0 && gx < H)
            v = *(const f16x8*)(inT + ((size_t)(b * H + gy) * H + gx) * 256 + cg * 8);
        int dst = (pos * 512 + cg * 16) ^ ((ix & 7) << 4);
        *(f16x8*)(sB + dst) = v;
    }
    __syncthreads();

    const int w = tid >> 6, lane = tid & 63;
    const int lcol = lane & 15, kg = lane >> 4;
    const int mt = mblk * 8 + w;
    const int q  = mt * 4 + kg;

    f32x4 acc[NT];
    f32x4 bv;
#pragma unroll
    for (int r = 0; r < 4; ++r) bv[r] = (q < PP) ? bias[r * PP + q] : 0.f;
#pragma unroll
    for (int nt = 0; nt < NT; ++nt) acc[nt] = bv;

#pragma unroll 1
    for (int k9 = 0; k9 < 9; ++k9) {
        const int ky = k9 / 3, kx = k9 % 3;
        int basev[NT], xswv[NT];
#pragma unroll
        for (int nt = 0; nt < NT; ++nt) {
            int p = nt * 16 + lcol;
            int pc = (NPX < 16 && p >= NPX) ? 0 : p;
            int py = pc / H, px = pc % H;
            int iy = py + ky, ix = px + kx;
            basev[nt] = (iy * SR + ix) * 512 + kg * 16;
            xswv[nt]  = (ix & 7) << 4;
        }
        const f16x8* apb = (const f16x8*)Apack + ((size_t)(k9 * 8) * 32 + mt) * 64 + lane;
#pragma unroll 1
        for (int ks = 0; ks < 8; ++ks) {
            f16x8 bf[NT];
#pragma unroll
            for (int nt = 0; nt < NT; ++nt) {
                bf[nt] = *(const f16x8*)(sB + ((basev[nt] + ks * 64) ^ xswv[nt]));
                if (NPX < 16 && nt * 16 + lcol >= NPX) bf[nt] = (f16x8){};
            }
            f16x8 af = apb[(size_t)ks * 32 * 64];
#pragma unroll
            for (int nt = 0; nt < NT; ++nt)
                acc[nt] = __builtin_amdgcn_mfma_f32_16x16x32_f16(af, bf[nt], acc[nt], 0, 0, 0);
        }
    }

    if (q < PP) {
#pragma unroll
        for (int nt = 0; nt < NT; ++nt) {
            int p = nt * 16 + lcol;
            if (NPX < 16 && p >= NPX) continue;
            int py = p / H, px = p % H;
            float ai = acc[nt][0];
            float af_ = acc[nt][1];
            float ao = acc[nt][2];
            float ag = acc[nt][3];
            float ig = 1.f / (1.f + expf(-ai));
            float fg = 1.f / (1.f + expf(-af_));
            float og = 1.f / (1.f + expf(-ao));
            float gg = tanhf(ag);
            size_t oidx = (((size_t)b * PP + q) * H + py) * H + px;
            float cp = cpre[oidx];
            float cn = fg * cp + ig * gg;
            outh[oidx] = og * tanhf(cn);
            outc[oidx] = cn;
        }
    }
}

__global__ __launch_bounds__(512, 4) void conv_tiny_kernel(
    TinyArgs ta, const _Float16* __restrict__ inT,
    const _Float16* __restrict__ a0, const _Float16* __restrict__ a1,
    const _Float16* __restrict__ a2)
{
    __shared__ char sB[100 * 512];
    const int z = blockIdx.z, b = blockIdx.y, mblk = blockIdx.x;
    if      (z == 0) conv_tiny_body<8>(inT,          ta.c[0], a0, ta.bi[0], ta.oh[0], ta.oc[0], b, mblk, sB);
    else if (z == 1) conv_tiny_body<4>(inT + 131072, ta.c[1], a1, ta.bi[1], ta.oh[1], ta.oc[1], b, mblk, sB);
    else             conv_tiny_body<2>(inT + 163840, ta.c[2], a2, ta.bi[2], ta.oh[2], ta.oc[2], b, mblk, sB);
}

// ---------------------------------------------------------------------------
extern "C" void kernel_launch(void* const* d_in, const int* in_sizes, int n_in,
                              void* d_out, int out_size, void* d_ws, size_t ws_size,
                              hipStream_t stream) {
    (void)in_sizes; (void)n_in; (void)out_size; (void)ws_size;
    static const int HH[6] = {64, 32, 16, 8, 4, 2};

    // ws layout (high-water 86,249,984 B — same as r6..r15):
    //   [256]          Apack0   (2,359,296)
    //   [2359808]      inT0     (16,777,216)  (also tiny inT at same base)
    //   [19137024]     xT       (33,554,432)  -- dead zone [+16.78MB..] after corr0
    //       Apack1 @ 44302848, Apack2 @ 46662144 (in dead xT zone)
    //       apT0/1/2 @ 19137024 + k*2359296 (after conv_all)
    //   [52691456]     xpT      (33,554,432)  -- dead zone [+16.78MB..] after corr0
    //       inT1 @ 77857280 (4,194,304), inT2 @ 82051584 (1,048,576)
    //   [86245888]     zg (4 KB)
    unsigned* maxslots = (unsigned*)d_ws;
    _Float16* Apack0 = (_Float16*)((char*)d_ws + 256);
    _Float16* inT    = (_Float16*)((char*)d_ws + 2359808);
    _Float16* xT     = (_Float16*)((char*)d_ws + 19137024);
    _Float16* xpT    = (_Float16*)((char*)d_ws + 52691456);
    _Float16* Apack1 = (_Float16*)((char*)d_ws + 44302848);
    _Float16* Apack2 = (_Float16*)((char*)d_ws + 46662144);
    _Float16* inT1   = (_Float16*)((char*)d_ws + 77857280);
    _Float16* inT2   = (_Float16*)((char*)d_ws + 82051584);
    _Float16* zg     = (_Float16*)((char*)d_ws + 86245888);
    _Float16* apT0   = (_Float16*)((char*)d_ws + 19137024);
    _Float16* apT1   = (_Float16*)((char*)d_ws + 19137024 + 2359296);
    _Float16* apT2   = (_Float16*)((char*)d_ws + 19137024 + 2 * 2359296);

    float* out = (float*)d_out;
    size_t obase[6];
    {
        size_t ob = 0;
        for (int L = 0; L < 6; ++L) { obase[L] = ob; ob += 2ull * NB * PP * HH[L] * HH[L]; }
    }

    init_kernel<<<1, 256, 0, stream>>>(maxslots, (float*)zg);

    // ---- big levels: tpose -> corr -> post (per level), then batched conv ----
    {
        const float* x0 = (const float*)d_in[0];  const float* xp0 = (const float*)d_in[1];
        const float* h0 = (const float*)d_in[2];  const float* W0  = (const float*)d_in[4];
        tpose_kernel<512, 64, 32><<<dim3(16, NB * 64, 2), 256, 0, stream>>>(x0, xp0, xT, xpT);
        corr_mfma_kernel<512, 64, 8, 8><<<dim3(64, NB), 512, 0, stream>>>(xT, xpT, zg, inT, maxslots + 0);
        post_kernel<64><<<256 + (NB * 64 * 64 * 17 + 255) / 256, 256, 0, stream>>>(inT, h0, W0, Apack0, maxslots + 0);

        const float* x1 = (const float*)d_in[6];  const float* xp1 = (const float*)d_in[7];
        const float* h1 = (const float*)d_in[8];  const float* W1  = (const float*)d_in[10];
        tpose_kernel<1024, 32, 32><<<dim3(16, NB * 32, 2), 256, 0, stream>>>(x1, xp1, xT, xpT);
        corr_mfma_kernel<1024, 32, 4, 8><<<dim3(32, NB), 512, 0, stream>>>(xT, xpT, zg, inT1, maxslots + 1);
        post_kernel<32><<<256 + (NB * 32 * 32 * 17 + 255) / 256, 256, 0, stream>>>(inT1, h1, W1, Apack1, maxslots + 1);

        const float* x2 = (const float*)d_in[12]; const float* xp2 = (const float*)d_in[13];
        const float* h2 = (const float*)d_in[14]; const float* W2  = (const float*)d_in[16];
        tpose_kernel<512, 16, 16><<<dim3(8, NB * 16, 2), 256, 0, stream>>>(x2, xp2, xT, xpT);
        corr_mfma_kernel<512, 16, 4, 4><<<dim3(16, NB), 512, 0, stream>>>(xT, xpT, zg, inT2, maxslots + 2);
        post_kernel<16><<<256 + (NB * 16 * 16 * 17 + 255) / 256, 256, 0, stream>>>(inT2, h2, W2, Apack2, maxslots + 2);

        ConvArgs ca;
        ca.inT0 = inT;  ca.inT1 = inT1; ca.inT2 = inT2;
        ca.c0 = (const float*)d_in[3];  ca.c1 = (const float*)d_in[9];  ca.c2 = (const float*)d_in[15];
        ca.ap0 = Apack0; ca.ap1 = Apack1; ca.ap2 = Apack2;
        ca.bi0 = (const float*)d_in[5]; ca.bi1 = (const float*)d_in[11]; ca.bi2 = (const float*)d_in[17];
        ca.oh0 = out + obase[0]; ca.oc0 = out + obase[0] + NB * PP * 64 * 64;
        ca.oh1 = out + obase[1]; ca.oc1 = out + obase[1] + NB * PP * 32 * 32;
        ca.oh2 = out + obase[2]; ca.oc2 = out + obase[2] + NB * PP * 16 * 16;
        ca.zg = zg;
        conv_all_kernel<<<896, 512, 0, stream>>>(ca);
    }

    // ---- tiny levels 3..5, batched ----
    TinyArgs ta;
    for (int i = 0; i < 3; ++i) {
        int L = 3 + i;
        ta.x[i]  = (const float*)d_in[6 * L + 0];
        ta.xp[i] = (const float*)d_in[6 * L + 1];
        ta.h[i]  = (const float*)d_in[6 * L + 2];
        ta.c[i]  = (const float*)d_in[6 * L + 3];
        ta.w[i]  = (const float*)d_in[6 * L + 4];
        ta.bi[i] = (const float*)d_in[6 * L + 5];
        int S = NB * PP * HH[L] * HH[L];
        ta.oh[i] = out + obase[L];
        ta.oc[i] = out + obase[L] + S;
    }
    tiny_corr_kernel<<<dim3(31, NB, 3), 256, 0, stream>>>(ta, inT, maxslots);
    tiny_hfill_kernel<<<dim3(5, NB, 3), 256, 0, stream>>>(ta, inT);
    pack_tiny_kernel<<<dim3(256, 1, 3), 256, 0, stream>>>(ta, apT0, apT1, apT2, maxslots);
    conv_tiny_kernel<<<dim3(4, NB, 3), 512, 0, stream>>>(ta, inT, apT0, apT1, apT2);
}

// Round 17
// 268.311 us; speedup vs baseline: 1.5381x; 1.3150x over previous
//
#include <hip/hip_runtime.h>
#include <hip/hip_bf16.h>
#include <cstdint>
#include <cstddef>

#define PD 11
#define PP 121
#define NB 8

typedef _Float16 f16x8 __attribute__((ext_vector_type(8)));
typedef float    f32x4 __attribute__((ext_vector_type(4)));

#define GLOAD16(SRC, DST) __builtin_amdgcn_global_load_lds( \
    (const __attribute__((address_space(1))) void*)(SRC),   \
    (__attribute__((address_space(3))) void*)(DST), 16, 0, 0)

struct TinyArgs {
    const float* x[3]; const float* xp[3]; const float* h[3];
    const float* c[3]; const float* w[3]; const float* bi[3];
    float* oh[3]; float* oc[3];
};

struct BigArgs {
    const float *x1, *xp1, *x2, *xp2;      // tpose inputs (K3)
    _Float16 *xT1, *xpT1, *xT2, *xpT2;
    _Float16 *inT0, *inT1, *inT2;
    const float *h0, *h1, *h2;
    const float *W0, *W1, *W2;
    _Float16 *ap0, *ap1, *ap2;
    unsigned* slots;
    const _Float16* zg;
};

struct ConvArgs {
    const _Float16 *inT0, *inT1, *inT2, *tinyInT;
    const float *c0, *c1, *c2;
    const _Float16 *ap0, *ap1, *ap2;
    const _Float16 *apT0, *apT1, *apT2;
    const float *bi0, *bi1, *bi2;
    float *oh0, *oc0, *oh1, *oc1, *oh2, *oc2;
    const _Float16* zg;
    TinyArgs ta;
};

// ---------------------------------------------------------------------------
__global__ void init_kernel(unsigned* __restrict__ slots, float* __restrict__ zg) {
    int t = threadIdx.x;
    if (t < 8) slots[t] = 0x007FFFFFu;  // enc(-inf)
    for (int i = t; i < 1024; i += 256) zg[i] = 0.f;
}

__device__ __forceinline__ float decode_max(const unsigned* slot) {
    unsigned mu = *slot;
    return (mu & 0x80000000u) ? __uint_as_float(mu ^ 0x80000000u) : __uint_as_float(~mu);
}

// ---------------------------------------------------------------------------
// fp32 NCHW -> fp16 NHWC transpose body (one image selected by caller)
template<int C, int H, int TPX>
__device__ void tpose_body(const float* __restrict__ in, _Float16* __restrict__ out,
                           int bx, int by, int tid, float (*s)[36])
{
    constexpr int W = H;
    const int b  = by / H, y = by % H;
    constexpr int NXT = W / TPX;
    const int x0 = (bx % NXT) * TPX;
    const int cc = (bx / NXT) * 64;

    constexpr int NF4 = 64 * TPX / 4;
    for (int f = tid; f < NF4; f += 256) {
        int r  = f / (TPX / 4);
        int xq = f % (TPX / 4);
        int col = (xq * 4) ^ (((r >> 3) & 7) * 4);
        *(float4*)&s[r][col] =
            *(const float4*)&in[((size_t)(b * C + cc + r) * H + y) * W + x0 + xq * 4];
    }
    __syncthreads();
    constexpr int NWT = TPX * 8;
    for (int t = tid; t < NWT; t += 256) {
        int pix = t >> 3, ck = t & 7;
        union { _Float16 h[8]; f16x8 v; } d;
#pragma unroll
        for (int j = 0; j < 8; ++j)
            d.h[j] = (_Float16)s[ck * 8 + j][pix ^ (ck * 4)];
        *(f16x8*)&out[((size_t)(b * H + y) * W + x0 + pix) * C + cc + ck * 8] = d.v;
    }
}

template<int C, int H, int TPX>
__global__ __launch_bounds__(256) void tpose_kernel(
    const float* __restrict__ xin, const float* __restrict__ xpin,
    _Float16* __restrict__ xT, _Float16* __restrict__ xpT)
{
    __shared__ float s[64][36];
    tpose_body<C, H, TPX>(blockIdx.z ? xpin : xin, blockIdx.z ? xpT : xT,
                          blockIdx.x, blockIdx.y, threadIdx.x, s);
}

// ---------------------------------------------------------------------------
// MFMA correlation body (r16-verified), explicit block coords + LDS.
template<int C, int H, int TSY, int TSX>
constexpr int corr_lds() {
    constexpr int HY = TSY + 10, HX = TSX + 10;
    constexpr int MZ = HY * HX;
    constexpr int MT = (MZ + 15) / 16;
    constexpr int MTP = MT * 16;
    constexpr int NPX = TSY * TSX;
    constexpr int BUF = (MTP + NPX) * 64;
    constexpr int ST2 = NPX + 8;
    constexpr int ST_B = MTP * ST2 * 2;
    return (2 * BUF > ST_B) ? 2 * BUF : ST_B;
}

template<int C, int H, int TSY, int TSX>
__device__ void corr_body(
    const _Float16* __restrict__ xT, const _Float16* __restrict__ xpT,
    const _Float16* __restrict__ zg,
    _Float16* __restrict__ inT, unsigned* __restrict__ slot,
    int bxt, int b, char* __restrict__ smem, float* __restrict__ sred)
{
    constexpr int W  = H;
    constexpr int HY = TSY + 10, HX = TSX + 10;
    constexpr int MZ = HY * HX;
    constexpr int MT = (MZ + 15) / 16;
    constexpr int MTP = MT * 16;
    constexpr int MFRAG = (MT + 7) / 8;
    constexpr int NPX = TSY * TSX;
    constexpr int NT  = NPX / 16;
    constexpr int KC  = C / 32;
    constexpr int ABYTES = MTP * 64;
    constexpr int BUF    = ABYTES + NPX * 64;
    constexpr int NLOAD  = BUF / 1024;
    constexpr int ST2    = NPX + 8;

    const int tid  = threadIdx.x;
    constexpr int TXT = W / TSX;
    const int y0 = (bxt / TXT) * TSY;
    const int x0 = (bxt % TXT) * TSX;
    const int w = tid >> 6, lane = tid & 63;
    const int lcol = lane & 15, lkg = lane >> 4;

    auto STAGE = [&](int bufsel, int kc) {
        char* dstb = smem + bufsel * BUF;
        int c = lane & 3;
        for (int it = w; it < NLOAD; it += 8) {
            const void* src;
            if (it < MTP / 16) {
                int z = it * 16 + (lane >> 2);
                int zy = y0 + z / HX - 5, zx = x0 + z % HX - 5;
                if (z < MZ && zy >= 0 && zy < H && zx >= 0 && zx < W)
                    src = xpT + ((size_t)(b * H + zy) * W + zx) * C + kc * 32 + ((c ^ (z >> 2)) & 3) * 8;
                else
                    src = zg + lane * 8;
            } else {
                int p = (it - MTP / 16) * 16 + (lane >> 2);
                int gy = y0 + p / TSX, gx = x0 + p % TSX;
                src = xT + ((size_t)(b * H + gy) * W + gx) * C + kc * 32 + ((c ^ (p >> 2)) & 3) * 8;
            }
            GLOAD16(src, dstb + it * 1024);
        }
    };

    f32x4 acc[MFRAG][NT];
#pragma unroll
    for (int i = 0; i < MFRAG; ++i)
#pragma unroll
        for (int nt = 0; nt < NT; ++nt)
            acc[i][nt] = (f32x4){0.f, 0.f, 0.f, 0.f};

    STAGE(0, 0);
    __syncthreads();
#pragma unroll 1
    for (int kc = 0; kc < KC; ++kc) {
        if (kc + 1 < KC) STAGE((kc + 1) & 1, kc + 1);
        const char* bb = smem + (kc & 1) * BUF;
        f16x8 bF[NT];
#pragma unroll
        for (int nt = 0; nt < NT; ++nt) {
            int p = nt * 16 + lcol;
            bF[nt] = *(const f16x8*)(bb + ABYTES + p * 64 + (((lkg ^ (p >> 2)) & 3) << 4));
        }
#pragma unroll
        for (int i = 0; i < MFRAG; ++i) {
            int mt = w + i * 8;
            if (mt < MT) {
                int z = mt * 16 + lcol;
                f16x8 aF = *(const f16x8*)(bb + z * 64 + (((lkg ^ (z >> 2)) & 3) << 4));
#pragma unroll
                for (int nt = 0; nt < NT; ++nt)
                    acc[i][nt] = __builtin_amdgcn_mfma_f32_16x16x32_f16(aF, bF[nt], acc[i][nt], 0, 0, 0);
            }
        }
        __syncthreads();
    }

    _Float16* sT = (_Float16*)smem;
#pragma unroll
    for (int i = 0; i < MFRAG; ++i) {
        int mt = w + i * 8;
        if (mt >= MT) continue;
        int z0 = mt * 16 + lkg * 4;
#pragma unroll
        for (int nt = 0; nt < NT; ++nt) {
            int p = nt * 16 + lcol;
#pragma unroll
            for (int r = 0; r < 4; ++r)
                sT[(z0 + r) * ST2 + p] = (_Float16)acc[i][nt][r];
        }
    }
    __syncthreads();

    float lmax = -3.4e38f;
    if (tid < NPX * 8) {
        int p  = tid >> 3;
        int qg = tid & 7;
        int py = p / TSX, px = p % TSX;
        size_t pix = (size_t)(b * H + y0 + py) * W + (x0 + px);
        unsigned* dst = (unsigned*)(inT + pix * 256) + qg * 8;
#pragma unroll
        for (int j2 = 0; j2 < 8; ++j2) {
            int q0 = qg * 16 + j2 * 2, q1 = q0 + 1;
            int qc0 = q0 < PP ? q0 : PP - 1;
            int qc1 = q1 < PP ? q1 : PP - 1;
            float v0 = (float)sT[((py + qc0 / PD) * HX + (px + qc0 % PD)) * ST2 + p];
            float v1 = (float)sT[((py + qc1 / PD) * HX + (px + qc1 % PD)) * ST2 + p];
            v0 = v0 > 0.f ? v0 : 0.01f * v0;
            v1 = v1 > 0.f ? v1 : 0.01f * v1;
            if (q0 < PP) lmax = fmaxf(lmax, v0);
            if (q1 < PP) lmax = fmaxf(lmax, v1);
            union { _Float16 h[2]; unsigned u; } pk;
            pk.h[0] = (_Float16)v0; pk.h[1] = (_Float16)v1;
            dst[j2] = pk.u;
        }
    }
    for (int off = 32; off; off >>= 1) lmax = fmaxf(lmax, __shfl_down(lmax, off));
    if (lane == 0) sred[w] = lmax;
    __syncthreads();
    if (tid == 0) {
        float m = sred[0];
        for (int i = 1; i < 8; ++i) m = fmaxf(m, sred[i]);
        unsigned eb = __float_as_uint(m);
        eb = (eb & 0x80000000u) ? ~eb : (eb | 0x80000000u);
        atomicMax(slot, eb);
    }
}

// standalone corr for L0
template<int C, int H, int TSY, int TSX>
__global__ __launch_bounds__(512, 2) void corr_mfma_kernel(
    const _Float16* __restrict__ xT, const _Float16* __restrict__ xpT,
    const _Float16* __restrict__ zg,
    _Float16* __restrict__ inT, unsigned* __restrict__ slot)
{
    __shared__ char smem[corr_lds<C, H, TSY, TSX>()];
    __shared__ float sred[8];
    corr_body<C, H, TSY, TSX>(xT, xpT, zg, inT, slot, blockIdx.x, blockIdx.y, smem, sred);
}

// ---------------------------------------------------------------------------
// coalesced weight pack body (LDS-staged, prescale corr columns by inv).
__device__ __forceinline__ void pack2_body(
    const float* __restrict__ Wsrc, _Float16* __restrict__ Apack,
    float inv, int mt, int ks, int tid, float* __restrict__ sW)
{
    const int icmax9 = (242 - ks * 32) * 9;
    for (int f = tid; f < 16 * 288; f += 256) {
        int r = f / 288, i = f - r * 288;
        int m = mt * 16 + r;
        float v = 0.f;
        if (m < 484 && i < icmax9) {
            int q = m >> 2, g = m & 3;
            v = Wsrc[((size_t)(g * PP + q) * 242 + ks * 32) * 9 + i];
        }
        sW[r * 292 + i] = v;
    }
    __syncthreads();
    const int o = tid * 2;
    const int l = o >> 3, e0 = o & 7;
    const int r = l & 15;
    const int klbase = (l >> 4) * 8;
    const int ic0 = ks * 32 + klbase + e0;
#pragma unroll 1
    for (int k9 = 0; k9 < 9; ++k9) {
        float v0 = sW[r * 292 + (klbase + e0) * 9 + k9];
        float v1 = sW[r * 292 + (klbase + e0 + 1) * 9 + k9];
        if (ic0 < PP)     v0 *= inv;
        if (ic0 + 1 < PP) v1 *= inv;
        union { _Float16 h[2]; unsigned u; } pk;
        pk.h[0] = (_Float16)v0; pk.h[1] = (_Float16)v1;
        *(unsigned*)((char*)Apack + (size_t)((k9 * 8 + ks) * 32 + mt) * 1024 + o * 2) = pk.u;
    }
}

// post body (pack blocks [0,256) + h-fill blocks above), explicit bx.
template<int H>
__device__ void post_body(
    _Float16* __restrict__ inT, const float* __restrict__ hpre,
    const float* __restrict__ Wsrc, _Float16* __restrict__ Apack,
    const unsigned* __restrict__ slot, int bx, int tid, float* __restrict__ sW)
{
    if (bx < 256) {
        float inv = 1.0f / decode_max(slot);
        pack2_body(Wsrc, Apack, inv, bx >> 3, bx & 7, tid, sW);
        return;
    }
    constexpr int HW = H * H;
    constexpr int NP = NB * HW;
    int idx = (bx - 256) * 256 + tid;
    if (idx >= NP * 17) return;
    int c = 15 + idx / NP;
    int pix = idx % NP;
    int b = pix / HW, p2 = pix % HW;
    _Float16* base = inT + (size_t)pix * 256 + c * 8;
    union { _Float16 h[8]; uint4 u; } d;
    if (c == 15) {
        d.u = *(const uint4*)base;
#pragma unroll
        for (int j = 1; j < 8; ++j)
            d.h[j] = (_Float16)hpre[((size_t)b * PP + (j - 1)) * HW + p2];
    } else if (c <= 29) {
#pragma unroll
        for (int j = 0; j < 8; ++j)
            d.h[j] = (_Float16)hpre[((size_t)b * PP + (c * 8 + j - 121)) * HW + p2];
    } else if (c == 30) {
        d.h[0] = (_Float16)hpre[((size_t)b * PP + 119) * HW + p2];
        d.h[1] = (_Float16)hpre[((size_t)b * PP + 120) * HW + p2];
#pragma unroll
        for (int j = 2; j < 8; ++j) d.h[j] = (_Float16)0.f;
    } else {
#pragma unroll
        for (int j = 0; j < 8; ++j) d.h[j] = (_Float16)0.f;
    }
    *(uint4*)base = d.u;
}

template<int H>
__global__ __launch_bounds__(256) void post_kernel(
    _Float16* __restrict__ inT, const float* __restrict__ hpre,
    const float* __restrict__ Wsrc, _Float16* __restrict__ Apack,
    const unsigned* __restrict__ slot)
{
    __shared__ float sW[16 * 292];
    post_body<H>(inT, hpre, Wsrc, Apack, slot, blockIdx.x, threadIdx.x, sW);
}

// ---------------------------------------------------------------------------
// tiny corr (512-thread variant), h-fill (256-thread), explicit coords.
template<int H>
__device__ void corr_small512_body(const float* __restrict__ x, const float* __restrict__ xp,
    _Float16* __restrict__ inT, unsigned* __restrict__ slot, int b, int bx,
    float* __restrict__ sred)
{
    constexpr int PX  = H * H;
    constexpr int TOT = PX * PP;
    const int tid = threadIdx.x;
    const int o = bx * 512 + tid;
    float v = -3.4e38f;
    if (o < TOT) {
        int p = o / PP;
        int q = o - p * PP;
        int y = p / H, xx = p % H;
        int sy = y + q / PD - 5, sx = xx + q % PD - 5;
        float acc = 0.f;
        if (sy >= 0 && sy < H && sx >= 0 && sx < H) {
            const float* xb  = x  + (size_t)b * 256 * PX + p;
            const float* xpb = xp + (size_t)b * 256 * PX + sy * H + sx;
#pragma unroll 8
            for (int c = 0; c < 256; ++c)
                acc = fmaf(xb[c * PX], xpb[c * PX], acc);
        }
        float lv = acc > 0.f ? acc : 0.01f * acc;
        inT[((size_t)b * PX + p) * 256 + q] = (_Float16)lv;
        v = lv;
    }
    for (int off = 32; off; off >>= 1) v = fmaxf(v, __shfl_down(v, off));
    if ((tid & 63) == 0) sred[tid >> 6] = v;
    __syncthreads();
    if (tid == 0) {
        float m = sred[0];
        for (int i = 1; i < 8; ++i) m = fmaxf(m, sred[i]);
        unsigned eb = __float_as_uint(m);
        eb = (eb & 0x80000000u) ? ~eb : (eb | 0x80000000u);
        atomicMax(slot, eb);
    }
}

template<int H>
__device__ void hfill_body(_Float16* __restrict__ inT, const float* __restrict__ hpre,
                           int b, int bx)
{
    constexpr int HW = H * H;
    int idx = bx * 256 + threadIdx.x;
    if (idx >= HW * 17) return;
    int c = 15 + idx / HW;
    int p2 = idx % HW;
    _Float16* base = inT + ((size_t)b * HW + p2) * 256 + c * 8;
    union { _Float16 h[8]; uint4 u; } d;
    if (c == 15) {
        d.u = *(const uint4*)base;
#pragma unroll
        for (int j = 1; j < 8; ++j)
            d.h[j] = (_Float16)hpre[((size_t)b * PP + (j - 1)) * HW + p2];
    } else if (c <= 29) {
#pragma unroll
        for (int j = 0; j < 8; ++j)
            d.h[j] = (_Float16)hpre[((size_t)b * PP + (c * 8 + j - 121)) * HW + p2];
    } else if (c == 30) {
        d.h[0] = (_Float16)hpre[((size_t)b * PP + 119) * HW + p2];
        d.h[1] = (_Float16)hpre[((size_t)b * PP + 120) * HW + p2];
#pragma unroll
        for (int j = 2; j < 8; ++j) d.h[j] = (_Float16)0.f;
    } else {
#pragma unroll
        for (int j = 0; j < 8; ++j) d.h[j] = (_Float16)0.f;
    }
    *(uint4*)base = d.u;
}

// ---------------------------------------------------------------------------
// K3: post0 + tpose1 + tpose2   (256 thr)
__global__ __launch_bounds__(256) void mixA_kernel(BigArgs ba, _Float16* __restrict__ inT0)
{
    __shared__ float sW[16 * 292];    // 18688 B (covers tpose's 9216 too)
    const int i = blockIdx.x, tid = threadIdx.x;
    if (i < 2432) {
        post_body<64>(inT0, ba.h0, ba.W0, ba.ap0, ba.slots + 0, i, tid, sW);
    } else if (i < 2432 + 8192) {
        int j = i - 2432;
        int z = j >> 12, r = j & 4095;
        tpose_body<1024, 32, 32>(z ? ba.xp1 : ba.x1, z ? ba.xpT1 : ba.xT1,
                                 r & 15, r >> 4, tid, (float(*)[36])sW);
    } else {
        int j = i - (2432 + 8192);
        int z = j >> 10, r = j & 1023;
        tpose_body<512, 16, 16>(z ? ba.xp2 : ba.x2, z ? ba.xpT2 : ba.xT2,
                                r & 7, r >> 3, tid, (float(*)[36])sW);
    }
}

// K4: corr1 + corr2 + tiny_corr  (512 thr)
__global__ __launch_bounds__(512, 2) void mixB_kernel(BigArgs ba, TinyArgs ta,
                                                      _Float16* __restrict__ tinyInT)
{
    __shared__ char smem[36864];
    __shared__ float sred[8];
    const int i = blockIdx.x;
    if (i < 256) {
        corr_body<1024, 32, 4, 8>(ba.xT1, ba.xpT1, ba.zg, ba.inT1, ba.slots + 1,
                                  i & 31, i >> 5, smem, sred);
    } else if (i < 384) {
        int j = i - 256;
        corr_body<512, 16, 4, 4>(ba.xT2, ba.xpT2, ba.zg, ba.inT2, ba.slots + 2,
                                 j & 15, j >> 4, smem, sred);
    } else if (i < 512) {
        int j = i - 384;
        corr_small512_body<8>(ta.x[0], ta.xp[0], tinyInT, ba.slots + 3,
                              j >> 4, j & 15, sred);
    } else if (i < 544) {
        int j = i - 512;
        corr_small512_body<4>(ta.x[1], ta.xp[1], tinyInT + 131072, ba.slots + 4,
                              j >> 2, j & 3, sred);
    } else {
        int j = i - 544;
        corr_small512_body<2>(ta.x[2], ta.xp[2], tinyInT + 163840, ba.slots + 5,
                              j, 0, sred);
    }
}

// K5: post1 + post2 + pack_tiny + tiny_hfill  (256 thr)
__global__ __launch_bounds__(256) void mixC_kernel(BigArgs ba, TinyArgs ta,
    _Float16* __restrict__ tinyInT,
    _Float16* __restrict__ apT0, _Float16* __restrict__ apT1, _Float16* __restrict__ apT2)
{
    __shared__ float sW[16 * 292];
    const int i = blockIdx.x, tid = threadIdx.x;
    if (i < 800) {
        post_body<32>(ba.inT1, ba.h1, ba.W1, ba.ap1, ba.slots + 1, i, tid, sW);
    } else if (i < 1192) {
        post_body<16>(ba.inT2, ba.h2, ba.W2, ba.ap2, ba.slots + 2, i - 800, tid, sW);
    } else if (i < 1960) {
        int j = i - 1192;
        int z = j >> 8, bx = j & 255;
        _Float16* Ap = (z == 0) ? apT0 : (z == 1 ? apT1 : apT2);
        float inv = 1.0f / decode_max(ba.slots + 3 + z);
        pack2_body(ta.w[z], Ap, inv, bx >> 3, bx & 7, tid, sW);
    } else {
        int j = i - 1960;
        if (j < 40)      hfill_body<8>(tinyInT,          ta.h[0], j / 5, j % 5);
        else if (j < 56) { int k = j - 40; hfill_body<4>(tinyInT + 131072, ta.h[1], k / 2, k % 2); }
        else             hfill_body<2>(tinyInT + 163840, ta.h[2], j - 56, 0);
    }
}

// ---------------------------------------------------------------------------
// conv v3 body (r15/r16-verified)
template<int H, int TR, int MSPLIT>
__device__ void conv_mfma3_body(
    const _Float16* __restrict__ inT, const float* __restrict__ cpre,
    const _Float16* __restrict__ Apack, const float* __restrict__ bias,
    const _Float16* __restrict__ zg,
    float* __restrict__ outh, float* __restrict__ outc,
    int tile, int b, int mblk, char* __restrict__ sB)
{
    constexpr int W = H;
    constexpr int TC = 16, SR = TC + 2;
    constexpr int NPOS = (TR + 2) * SR;
    constexpr int MT_BLK = 32 / MSPLIT;
    constexpr int AF = 4 / MSPLIT;
    constexpr int TILES_X = W / TC;

    const int tid  = threadIdx.x;
    const int ty0  = (tile / TILES_X) * TR;
    const int tx0  = (tile % TILES_X) * TC;
    const int w = tid >> 6, lane = tid & 63;
    const int lcol = lane & 15, kg = lane >> 4;

    for (int it = w; it < NPOS / 2; it += 8) {
        int r  = it * 2 + (lane >> 5);
        int c  = lane & 31;
        int iy = r / SR, ix = r % SR;
        int gy = ty0 + iy - 1, gx = tx0 + ix - 1;
        const void* src;
        if (gy >= 0 && gy < H && gx >= 0 && gx < W)
            src = inT + ((size_t)(b * H + gy) * W + gx) * 256 + (c ^ (ix & 7)) * 8;
        else
            src = zg + lane * 8;
        GLOAD16(src, sB + it * 1024);
    }
    __syncthreads();

    const int mtg0 = mblk * MT_BLK + w * AF;

    f32x4 acc[AF * TR];
#pragma unroll
    for (int a = 0; a < AF; ++a) {
        int q = (mtg0 + a) * 4 + kg;
        f32x4 bv;
#pragma unroll
        for (int r = 0; r < 4; ++r) bv[r] = (q < PP) ? bias[r * PP + q] : 0.f;
#pragma unroll
        for (int j = 0; j < TR; ++j) acc[a * TR + j] = bv;
    }

    const f16x8* apL = (const f16x8*)Apack + (size_t)mtg0 * 64 + lane;

    auto COMPUTE = [&](const f16x8* af, int s) {
        int k9 = s >> 3, ks = s & 7;
        int ky = k9 / 3, kx = k9 - ky * 3;
        int ix = lcol + kx;
        int xsw = (ix & 7) << 4;
        int cb  = kg * 16 + ks * 64;
        __builtin_amdgcn_s_setprio(1);
#pragma unroll
        for (int j = 0; j < TR; ++j) {
            int addr = ((((j + ky) * SR + ix) * 512) + cb) ^ xsw;
            f16x8 bf = *(const f16x8*)(sB + addr);
#pragma unroll
            for (int a = 0; a < AF; ++a)
                acc[a * TR + j] = __builtin_amdgcn_mfma_f32_16x16x32_f16(af[a], bf, acc[a * TR + j], 0, 0, 0);
        }
        __builtin_amdgcn_s_setprio(0);
    };

    f16x8 afA[AF], afB[AF];
#pragma unroll
    for (int a = 0; a < AF; ++a) afA[a] = apL[a * 64];
#pragma unroll 1
    for (int s2 = 0; s2 < 36; ++s2) {
        const f16x8* apB = apL + (size_t)(s2 * 2 + 1) * 2048;
#pragma unroll
        for (int a = 0; a < AF; ++a) afB[a] = apB[a * 64];
        COMPUTE(afA, s2 * 2);
        if (s2 < 35) {
            const f16x8* apA = apL + (size_t)(s2 * 2 + 2) * 2048;
#pragma unroll
            for (int a = 0; a < AF; ++a) afA[a] = apA[a * 64];
        }
        COMPUTE(afB, s2 * 2 + 1);
    }

#pragma unroll
    for (int a = 0; a < AF; ++a) {
        int q = (mtg0 + a) * 4 + kg;
        if (q >= PP) continue;
#pragma unroll
        for (int j = 0; j < TR; ++j) {
            int y = ty0 + j, x = tx0 + lcol;
            if (y >= H) continue;
            float ai = acc[a * TR + j][0];
            float af_ = acc[a * TR + j][1];
            float ao = acc[a * TR + j][2];
            float ag = acc[a * TR + j][3];
            float ig = 1.f / (1.f + expf(-ai));
            float fg = 1.f / (1.f + expf(-af_));
            float og = 1.f / (1.f + expf(-ao));
            float gg = tanhf(ag);
            size_t oidx = (((size_t)b * PP + q) * H + y) * W + x;
            float cp = cpre[oidx];
            float cn = fg * cp + ig * gg;
            outh[oidx] = og * tanhf(cn);
            outc[oidx] = cn;
        }
    }
}

// tiny conv body (r16-verified)
template<int H>
__device__ void conv_tiny_body(const _Float16* __restrict__ inT,
    const float* __restrict__ cpre, const _Float16* __restrict__ Apack,
    const float* __restrict__ bias, float* __restrict__ outh,
    float* __restrict__ outc, int b, int mblk, char* __restrict__ sB)
{
    constexpr int NPX = H * H;
    constexpr int NT  = (NPX + 15) / 16;
    constexpr int SR  = H + 2;
    constexpr int NPOS = SR * SR;
    const int tid = threadIdx.x;

    constexpr int CHUNKS = NPOS * 32;
    for (int flat = tid; flat < CHUNKS; flat += 512) {
        int cg  = flat & 31;
        int pos = flat >> 5;
        int iy = pos / SR, ix = pos % SR;
        int gy = iy - 1, gx = ix - 1;
        f16x8 v = {0, 0, 0, 0, 0, 0, 0, 0};
        if (gy >= 0 && gy < H && gx >= 0 && gx < H)
            v = *(const f16x8*)(inT + ((size_t)(b * H + gy) * H + gx) * 256 + cg * 8);
        int dst = (pos * 512 + cg * 16) ^ ((ix & 7) << 4);
        *(f16x8*)(sB + dst) = v;
    }
    __syncthreads();

    const int w = tid >> 6, lane = tid & 63;
    const int lcol = lane & 15, kg = lane >> 4;
    const int mt = mblk * 8 + w;
    const int q  = mt * 4 + kg;

    f32x4 acc[NT];
    f32x4 bv;
#pragma unroll
    for (int r = 0; r < 4; ++r) bv[r] = (q < PP) ? bias[r * PP + q] : 0.f;
#pragma unroll
    for (int nt = 0; nt < NT; ++nt) acc[nt] = bv;

#pragma unroll 1
    for (int k9 = 0; k9 < 9; ++k9) {
        const int ky = k9 / 3, kx = k9 % 3;
        int basev[NT], xswv[NT];
#pragma unroll
        for (int nt = 0; nt < NT; ++nt) {
            int p = nt * 16 + lcol;
            int pc = (NPX < 16 && p >= NPX) ? 0 : p;
            int py = pc / H, px = pc % H;
            int iy = py + ky, ix = px + kx;
            basev[nt] = (iy * SR + ix) * 512 + kg * 16;
            xswv[nt]  = (ix & 7) << 4;
        }
        const f16x8* apb = (const f16x8*)Apack + ((size_t)(k9 * 8) * 32 + mt) * 64 + lane;
#pragma unroll 1
        for (int ks = 0; ks < 8; ++ks) {
            f16x8 bf[NT];
#pragma unroll
            for (int nt = 0; nt < NT; ++nt) {
                bf[nt] = *(const f16x8*)(sB + ((basev[nt] + ks * 64) ^ xswv[nt]));
                if (NPX < 16 && nt * 16 + lcol >= NPX) bf[nt] = (f16x8){};
            }
            f16x8 af = apb[(size_t)ks * 32 * 64];
#pragma unroll
            for (int nt = 0; nt < NT; ++nt)
                acc[nt] = __builtin_amdgcn_mfma_f32_16x16x32_f16(af, bf[nt], acc[nt], 0, 0, 0);
        }
    }

    if (q < PP) {
#pragma unroll
        for (int nt = 0; nt < NT; ++nt) {
            int p = nt * 16 + lcol;
            if (NPX < 16 && p >= NPX) continue;
            int py = p / H, px = p % H;
            float ai = acc[nt][0];
            float af_ = acc[nt][1];
            float ao = acc[nt][2];
            float ag = acc[nt][3];
            float ig = 1.f / (1.f + expf(-ai));
            float fg = 1.f / (1.f + expf(-af_));
            float og = 1.f / (1.f + expf(-ao));
            float gg = tanhf(ag);
            size_t oidx = (((size_t)b * PP + q) * H + py) * H + px;
            float cp = cpre[oidx];
            float cn = fg * cp + ig * gg;
            outh[oidx] = og * tanhf(cn);
            outc[oidx] = cn;
        }
    }
}

// K6: conv_all (896) + conv_tiny (96)
__global__ __launch_bounds__(512, 4) void conv_combo_kernel(ConvArgs ca)
{
    __shared__ char sB[108 * 512];
    const int bx = blockIdx.x;
    if (bx < 512) {
        conv_mfma3_body<64, 4, 1>(ca.inT0, ca.c0, ca.ap0, ca.bi0, ca.zg,
                                  ca.oh0, ca.oc0, bx & 63, bx >> 6, 0, sB);
    } else if (bx < 768) {
        int i = bx - 512;
        conv_mfma3_body<32, 4, 2>(ca.inT1, ca.c1, ca.ap1, ca.bi1, ca.zg,
                                  ca.oh1, ca.oc1, i & 15, (i >> 4) & 7, i >> 7, sB);
    } else if (bx < 896) {
        int i = bx - 768;
        conv_mfma3_body<16, 4, 4>(ca.inT2, ca.c2, ca.ap2, ca.bi2, ca.zg,
                                  ca.oh2, ca.oc2, i & 3, (i >> 2) & 7, i >> 5, sB);
    } else {
        int j = bx - 896;
        int z = j >> 5, r = j & 31;
        int b = r >> 2, mblk = r & 3;
        if      (z == 0) conv_tiny_body<8>(ca.tinyInT,          ca.ta.c[0], ca.apT0, ca.ta.bi[0], ca.ta.oh[0], ca.ta.oc[0], b, mblk, sB);
        else if (z == 1) conv_tiny_body<4>(ca.tinyInT + 131072, ca.ta.c[1], ca.apT1, ca.ta.bi[1], ca.ta.oh[1], ca.ta.oc[1], b, mblk, sB);
        else             conv_tiny_body<2>(ca.tinyInT + 163840, ca.ta.c[2], ca.apT2, ca.ta.bi[2], ca.ta.oh[2], ca.ta.oc[2], b, mblk, sB);
    }
}

// ---------------------------------------------------------------------------
extern "C" void kernel_launch(void* const* d_in, const int* in_sizes, int n_in,
                              void* d_out, int out_size, void* d_ws, size_t ws_size,
                              hipStream_t stream) {
    (void)in_sizes; (void)n_in; (void)out_size; (void)ws_size;
    static const int HH[6] = {64, 32, 16, 8, 4, 2};

    // ws layout (high-water 86,249,984 B):
    //  [256]       Apack0 (2,359,296)
    //  [2359808]   inT0   (16,777,216)
    //  XB=19137024 (33,554,432): xT0 full | after corr0: xT1 @+0, xpT1 @+16,777,216
    //  PB=52691456 (33,554,432): xpT0 full | after corr0:
    //     xT2 @+0 (2.1M), xpT2 @+2097152, inT1 @+4194304 (4.2M), inT2 @+8388608 (1.05M),
    //     Apack1 @+9437184, Apack2 @+11796480, tinyInT @+16777216 (344K),
    //     apT0 @+17825792, apT1 @+20185088, apT2 @+22544384 (ends +24,903,680)
    //  [86245888]  zg (4 KB)
    char* W = (char*)d_ws;
    unsigned* maxslots = (unsigned*)W;
    _Float16* Apack0 = (_Float16*)(W + 256);
    _Float16* inT0   = (_Float16*)(W + 2359808);
    char* XB = W + 19137024;
    char* PB = W + 52691456;
    _Float16* xT0  = (_Float16*)XB;
    _Float16* xpT0 = (_Float16*)PB;
    _Float16* zg   = (_Float16*)(W + 86245888);

    BigArgs ba;
    ba.x1  = (const float*)d_in[6];  ba.xp1 = (const float*)d_in[7];
    ba.x2  = (const float*)d_in[12]; ba.xp2 = (const float*)d_in[13];
    ba.xT1  = (_Float16*)(XB + 0);
    ba.xpT1 = (_Float16*)(XB + 16777216);
    ba.xT2  = (_Float16*)(PB + 0);
    ba.xpT2 = (_Float16*)(PB + 2097152);
    ba.inT0 = inT0;
    ba.inT1 = (_Float16*)(PB + 4194304);
    ba.inT2 = (_Float16*)(PB + 8388608);
    ba.h0 = (const float*)d_in[2];  ba.h1 = (const float*)d_in[8];  ba.h2 = (const float*)d_in[14];
    ba.W0 = (const float*)d_in[4];  ba.W1 = (const float*)d_in[10]; ba.W2 = (const float*)d_in[16];
    ba.ap0 = Apack0;
    ba.ap1 = (_Float16*)(PB + 9437184);
    ba.ap2 = (_Float16*)(PB + 11796480);
    ba.slots = maxslots;
    ba.zg = zg;
    _Float16* tinyInT = (_Float16*)(PB + 16777216);
    _Float16* apT0 = (_Float16*)(PB + 17825792);
    _Float16* apT1 = (_Float16*)(PB + 20185088);
    _Float16* apT2 = (_Float16*)(PB + 22544384);

    float* out = (float*)d_out;
    size_t obase[6];
    {
        size_t ob = 0;
        for (int L = 0; L < 6; ++L) { obase[L] = ob; ob += 2ull * NB * PP * HH[L] * HH[L]; }
    }

    TinyArgs ta;
    for (int i = 0; i < 3; ++i) {
        int L = 3 + i;
        ta.x[i]  = (const float*)d_in[6 * L + 0];
        ta.xp[i] = (const float*)d_in[6 * L + 1];
        ta.h[i]  = (const float*)d_in[6 * L + 2];
        ta.c[i]  = (const float*)d_in[6 * L + 3];
        ta.w[i]  = (const float*)d_in[6 * L + 4];
        ta.bi[i] = (const float*)d_in[6 * L + 5];
        int S = NB * PP * HH[L] * HH[L];
        ta.oh[i] = out + obase[L];
        ta.oc[i] = out + obase[L] + S;
    }

    // K0
    init_kernel<<<1, 256, 0, stream>>>(maxslots, (float*)zg);
    // K1: tpose L0
    tpose_kernel<512, 64, 32><<<dim3(16, NB * 64, 2), 256, 0, stream>>>(
        (const float*)d_in[0], (const float*)d_in[1], xT0, xpT0);
    // K2: corr L0
    corr_mfma_kernel<512, 64, 8, 8><<<dim3(64, NB), 512, 0, stream>>>(
        xT0, xpT0, zg, inT0, maxslots + 0);
    // K3: post0 + tpose1 + tpose2
    mixA_kernel<<<2432 + 8192 + 2048, 256, 0, stream>>>(ba, inT0);
    // K4: corr1 + corr2 + tiny corr
    mixB_kernel<<<552, 512, 0, stream>>>(ba, ta, tinyInT);
    // K5: post1 + post2 + pack_tiny + tiny h-fill
    mixC_kernel<<<2024, 256, 0, stream>>>(ba, ta, tinyInT, apT0, apT1, apT2);
    // K6: conv all levels + tiny
    ConvArgs ca;
    ca.inT0 = inT0; ca.inT1 = ba.inT1; ca.inT2 = ba.inT2; ca.tinyInT = tinyInT;
    ca.c0 = (const float*)d_in[3];  ca.c1 = (const float*)d_in[9];  ca.c2 = (const float*)d_in[15];
    ca.ap0 = Apack0; ca.ap1 = ba.ap1; ca.ap2 = ba.ap2;
    ca.apT0 = apT0; ca.apT1 = apT1; ca.apT2 = apT2;
    ca.bi0 = (const float*)d_in[5]; ca.bi1 = (const float*)d_in[11]; ca.bi2 = (const float*)d_in[17];
    ca.oh0 = out + obase[0]; ca.oc0 = out + obase[0] + NB * PP * 64 * 64;
    ca.oh1 = out + obase[1]; ca.oc1 = out + obase[1] + NB * PP * 32 * 32;
    ca.oh2 = out + obase[2]; ca.oc2 = out + obase[2] + NB * PP * 16 * 16;
    ca.zg = zg;
    ca.ta = ta;
    conv_combo_kernel<<<896 + 96, 512, 0, stream>>>(ca);
}